// Round 11
// baseline (259.132 us; speedup 1.0000x reference)
//
#include <hip/hip_runtime.h>
#include <hip/hip_fp16.h>

#define NN 50000
#define NE 800000
#define INFEAT 128
#define F1 256
#define HID 64
#define CLS 40
#define NEGS 0.2f
#define NB 49   // ceil(NN / 1024)

__device__ __forceinline__ float lrelu(float x) { return x > 0.0f ? x : NEGS * x; }

struct alignas(8) H4 { __half2 a, b; };
struct alignas(16) H8 { __half2 a, b, c, d; };

// ---------------- GEMM1: fea1h = fp16(x @ W1 + b1), fused per-node scores ----------------
// 128x128 block tile (2 heads), 8x8 per thread -> 64 FMA per 4 LDS b128 reads per k
#define BM 128
#define BN2 128
#define BK 32
__global__ __launch_bounds__(256) void gemm1_k(const float* __restrict__ A,
                                               const float* __restrict__ W,
                                               const float* __restrict__ b,
                                               const float* __restrict__ att1,
                                               __half* __restrict__ feah,
                                               float* __restrict__ sI,
                                               float* __restrict__ sJ) {
    __shared__ float As[BK][BM + 4];    // transposed A tile
    __shared__ float Bs[BK][BN2 + 4];
    int tid = threadIdx.x;
    int row0 = blockIdx.x * BM;
    int colB = blockIdx.y * BN2;        // 0 or 128
    int tx = tid & 15, ty = tid >> 4;   // 16x16 thread grid
    // A staging: 32 row-lanes x 8 col-lanes, 4 row iterations
    int ar = tid >> 3;                  // 0..31
    int ac = (tid & 7) * 4;             // 0..28
    // B staging: 8 k-rows x 32 col-lanes, 4 k iterations
    int bkr = tid >> 5;                 // 0..7
    int bkc = (tid & 31) * 4;           // 0..124
    float4 pa[4], pb[4];
    auto load_tile = [&](int k0) {
        #pragma unroll
        for (int i = 0; i < 4; ++i) {
            int grow = row0 + ar + i * 32;
            pa[i] = (grow < NN) ? *(const float4*)&A[(size_t)grow * INFEAT + k0 + ac]
                                : make_float4(0.f, 0.f, 0.f, 0.f);
        }
        #pragma unroll
        for (int i = 0; i < 4; ++i)
            pb[i] = *(const float4*)&W[(size_t)(k0 + bkr + i * 8) * F1 + colB + bkc];
    };
    float acc[8][8] = {};
    load_tile(0);
    for (int k0 = 0; k0 < INFEAT; k0 += BK) {
        #pragma unroll
        for (int i = 0; i < 4; ++i) {
            int rr = ar + i * 32;
            As[ac + 0][rr] = pa[i].x; As[ac + 1][rr] = pa[i].y;
            As[ac + 2][rr] = pa[i].z; As[ac + 3][rr] = pa[i].w;
        }
        #pragma unroll
        for (int i = 0; i < 4; ++i)
            *(float4*)&Bs[bkr + i * 8][bkc] = pb[i];
        __syncthreads();
        if (k0 + BK < INFEAT) load_tile(k0 + BK);
        #pragma unroll
        for (int k = 0; k < BK; ++k) {
            float4 a0 = *(const float4*)&As[k][ty * 8];
            float4 a1 = *(const float4*)&As[k][ty * 8 + 4];
            float4 b0 = *(const float4*)&Bs[k][tx * 8];
            float4 b1 = *(const float4*)&Bs[k][tx * 8 + 4];
            float a[8] = {a0.x, a0.y, a0.z, a0.w, a1.x, a1.y, a1.z, a1.w};
            float bb[8] = {b0.x, b0.y, b0.z, b0.w, b1.x, b1.y, b1.z, b1.w};
            #pragma unroll
            for (int i = 0; i < 8; ++i)
                #pragma unroll
                for (int j = 0; j < 8; ++j) acc[i][j] += a[i] * bb[j];
        }
        __syncthreads();
    }
    // epilogue: bias + fp16 store + fused per-head scores
    int head = blockIdx.y * 2 + (tx >> 3);
    int colb = colB + tx * 8;           // global column of acc[i][0]
    int cin  = (tx & 7) * 8;            // column within head
    float4 bv0 = *(const float4*)&b[colb];
    float4 bv1 = *(const float4*)&b[colb + 4];
    float bias8[8] = {bv0.x, bv0.y, bv0.z, bv0.w, bv1.x, bv1.y, bv1.z, bv1.w};
    float aI[8], aJ[8];
    #pragma unroll
    for (int j = 0; j < 8; ++j) {
        aI[j] = att1[head * 2 * HID + cin + j];
        aJ[j] = att1[head * 2 * HID + HID + cin + j];
    }
    #pragma unroll
    for (int i = 0; i < 8; ++i) {
        int grow = row0 + ty * 8 + i;
        float o[8];
        #pragma unroll
        for (int j = 0; j < 8; ++j) o[j] = acc[i][j] + bias8[j];
        if (grow < NN) {
            H8 v;
            v.a = __floats2half2_rn(o[0], o[1]);
            v.b = __floats2half2_rn(o[2], o[3]);
            v.c = __floats2half2_rn(o[4], o[5]);
            v.d = __floats2half2_rn(o[6], o[7]);
            *(H8*)&feah[(size_t)grow * F1 + colb] = v;
        }
        float sIp = 0.f, sJp = 0.f;
        #pragma unroll
        for (int j = 0; j < 8; ++j) { sIp += o[j] * aI[j]; sJp += o[j] * aJ[j]; }
        #pragma unroll
        for (int off = 1; off < 8; off <<= 1) {
            sIp += __shfl_xor(sIp, off);
            sJp += __shfl_xor(sJp, off);
        }
        if ((tx & 7) == 0 && grow < NN) {
            sI[grow * 4 + head] = sIp;
            sJ[grow * 4 + head] = sJp;
        }
    }
}

// ---------------- CSR build: histogram harvests the ordinal ----------------
__global__ void hist_k(const int* __restrict__ dst, int* __restrict__ deg,
                       int* __restrict__ ord) {
    int e = blockIdx.x * blockDim.x + threadIdx.x;
    if (e < NE) ord[e] = atomicAdd(&deg[dst[e]], 1);
}

// hierarchical scan: 49 blocks of 1024, then 1-wave scan of block sums, then add-back
__global__ __launch_bounds__(1024) void scan1_k(const int* __restrict__ deg,
                                                int* __restrict__ row_off,
                                                int* __restrict__ bsum) {
    __shared__ int tmp[1024];
    int tid = threadIdx.x;
    int gid = blockIdx.x * 1024 + tid;
    int v = (gid < NN) ? deg[gid] : 0;
    tmp[tid] = v;
    __syncthreads();
    #pragma unroll
    for (int off = 1; off < 1024; off <<= 1) {
        int t = (tid >= off) ? tmp[tid - off] : 0;
        __syncthreads();
        tmp[tid] += t;
        __syncthreads();
    }
    if (gid < NN) row_off[gid] = tmp[tid] - v;   // exclusive
    if (tid == 1023) bsum[blockIdx.x] = tmp[1023];
}

__global__ void scan2_k(const int* __restrict__ bsum, int* __restrict__ bpref) {
    int tid = threadIdx.x;           // 64 threads, one wave
    int orig = (tid < NB) ? bsum[tid] : 0;
    int v = orig;
    #pragma unroll
    for (int off = 1; off < 64; off <<= 1) {
        int t = __shfl_up(v, off);
        if (tid >= off) v += t;
    }
    if (tid < NB) bpref[tid] = v - orig;   // exclusive block prefix
}

__global__ __launch_bounds__(1024) void scan3_k(int* __restrict__ row_off,
                                                const int* __restrict__ bpref) {
    int gid = blockIdx.x * 1024 + threadIdx.x;
    if (gid < NN) row_off[gid] += bpref[blockIdx.x];
    if (gid == 0) row_off[NN] = NE;      // total degree is exactly NE
}

// ---------------- scatter: atomic-free (pos = row_off[dst] + ord), fused ep1 ----------------
__global__ void scatter_k(const int* __restrict__ src, const int* __restrict__ dst,
                          const int* __restrict__ ord, const int* __restrict__ row_off,
                          const float* __restrict__ sI, const float* __restrict__ sJ,
                          int* __restrict__ csr, float4* __restrict__ ep4) {
    int e = blockIdx.x * blockDim.x + threadIdx.x;
    if (e >= NE) return;
    int s = src[e], d = dst[e];
    int pos = row_off[d] + ord[e];
    float4 si = *(const float4*)&sI[d * 4];
    float4 sj = *(const float4*)&sJ[s * 4];
    float4 r;
    r.x = __expf(lrelu(si.x + sj.x));
    r.y = __expf(lrelu(si.y + sj.y));
    r.z = __expf(lrelu(si.z + sj.z));
    r.w = __expf(lrelu(si.w + sj.w));
    csr[pos] = s;
    ep4[pos] = r;
}

// ---------------- layer-1 aggregation: streams precomputed ep, fp16 row gathers ----------------
__global__ __launch_bounds__(256, 6) void agg1_k(const __half* __restrict__ feah,
                                                 const float* __restrict__ sI,
                                                 const float* __restrict__ sJ,
                                                 const float* __restrict__ epf,
                                                 const int* __restrict__ row_off,
                                                 const int* __restrict__ csr,
                                                 const float* __restrict__ bias,
                                                 float* __restrict__ out) {
    int wid = threadIdx.x >> 6, lane = threadIdx.x & 63;
    int n = blockIdx.x * 4 + wid;
    if (n >= NN) return;
    int h = lane >> 4;           // head of this lane's channels
    int c = lane * 4;            // channel group
    // self loop
    float p = __expf(lrelu(sI[n * 4 + h] + sJ[n * 4 + h]));
    float asum = p;
    H4 vs = *(const H4*)&feah[(size_t)n * F1 + c];
    float2 sx = __half22float2(vs.a), sy = __half22float2(vs.b);
    float4 acc = make_float4(sx.x * p, sx.y * p, sy.x * p, sy.y * p);
    int beg = row_off[n], end = row_off[n + 1];
    int e = beg;
    for (; e + 8 <= end; e += 8) {
        int s0 = csr[e + 0], s1 = csr[e + 1], s2 = csr[e + 2], s3 = csr[e + 3];
        int s4 = csr[e + 4], s5 = csr[e + 5], s6 = csr[e + 6], s7 = csr[e + 7];
        float p0 = epf[(e + 0) * 4 + h], p1 = epf[(e + 1) * 4 + h];
        float p2 = epf[(e + 2) * 4 + h], p3 = epf[(e + 3) * 4 + h];
        float p4 = epf[(e + 4) * 4 + h], p5 = epf[(e + 5) * 4 + h];
        float p6 = epf[(e + 6) * 4 + h], p7 = epf[(e + 7) * 4 + h];
        H4 v0 = *(const H4*)&feah[(size_t)s0 * F1 + c];
        H4 v1 = *(const H4*)&feah[(size_t)s1 * F1 + c];
        H4 v2 = *(const H4*)&feah[(size_t)s2 * F1 + c];
        H4 v3 = *(const H4*)&feah[(size_t)s3 * F1 + c];
        H4 v4 = *(const H4*)&feah[(size_t)s4 * F1 + c];
        H4 v5 = *(const H4*)&feah[(size_t)s5 * F1 + c];
        H4 v6 = *(const H4*)&feah[(size_t)s6 * F1 + c];
        H4 v7 = *(const H4*)&feah[(size_t)s7 * F1 + c];
        asum += ((p0 + p1) + (p2 + p3)) + ((p4 + p5) + (p6 + p7));
        float2 x0 = __half22float2(v0.a), y0 = __half22float2(v0.b);
        float2 x1 = __half22float2(v1.a), y1 = __half22float2(v1.b);
        float2 x2 = __half22float2(v2.a), y2 = __half22float2(v2.b);
        float2 x3 = __half22float2(v3.a), y3 = __half22float2(v3.b);
        float2 x4 = __half22float2(v4.a), y4 = __half22float2(v4.b);
        float2 x5 = __half22float2(v5.a), y5 = __half22float2(v5.b);
        float2 x6 = __half22float2(v6.a), y6 = __half22float2(v6.b);
        float2 x7 = __half22float2(v7.a), y7 = __half22float2(v7.b);
        acc.x += (x0.x * p0 + x1.x * p1 + x2.x * p2 + x3.x * p3)
               + (x4.x * p4 + x5.x * p5 + x6.x * p6 + x7.x * p7);
        acc.y += (x0.y * p0 + x1.y * p1 + x2.y * p2 + x3.y * p3)
               + (x4.y * p4 + x5.y * p5 + x6.y * p6 + x7.y * p7);
        acc.z += (y0.x * p0 + y1.x * p1 + y2.x * p2 + y3.x * p3)
               + (y4.x * p4 + y5.x * p5 + y6.x * p6 + y7.x * p7);
        acc.w += (y0.y * p0 + y1.y * p1 + y2.y * p2 + y3.y * p3)
               + (y4.y * p4 + y5.y * p5 + y6.y * p6 + y7.y * p7);
    }
    for (; e + 4 <= end; e += 4) {
        int s0 = csr[e], s1 = csr[e + 1], s2 = csr[e + 2], s3 = csr[e + 3];
        float p0 = epf[(e + 0) * 4 + h], p1 = epf[(e + 1) * 4 + h];
        float p2 = epf[(e + 2) * 4 + h], p3 = epf[(e + 3) * 4 + h];
        H4 v0 = *(const H4*)&feah[(size_t)s0 * F1 + c];
        H4 v1 = *(const H4*)&feah[(size_t)s1 * F1 + c];
        H4 v2 = *(const H4*)&feah[(size_t)s2 * F1 + c];
        H4 v3 = *(const H4*)&feah[(size_t)s3 * F1 + c];
        asum += (p0 + p1) + (p2 + p3);
        float2 x0 = __half22float2(v0.a), y0 = __half22float2(v0.b);
        float2 x1 = __half22float2(v1.a), y1 = __half22float2(v1.b);
        float2 x2 = __half22float2(v2.a), y2 = __half22float2(v2.b);
        float2 x3 = __half22float2(v3.a), y3 = __half22float2(v3.b);
        acc.x += x0.x * p0 + x1.x * p1 + x2.x * p2 + x3.x * p3;
        acc.y += x0.y * p0 + x1.y * p1 + x2.y * p2 + x3.y * p3;
        acc.z += y0.x * p0 + y1.x * p1 + y2.x * p2 + y3.x * p3;
        acc.w += y0.y * p0 + y1.y * p1 + y2.y * p2 + y3.y * p3;
    }
    for (; e < end; ++e) {
        int s = csr[e];
        float pe = epf[e * 4 + h];
        asum += pe;
        H4 v = *(const H4*)&feah[(size_t)s * F1 + c];
        float2 x = __half22float2(v.a), y = __half22float2(v.b);
        acc.x += x.x * pe; acc.y += x.y * pe;
        acc.z += y.x * pe; acc.w += y.y * pe;
    }
    float inv = 1.0f / (asum + 1e-16f);
    float4 bv = *(const float4*)&bias[c];
    float4 o;
    o.x = fmaxf(acc.x * inv + bv.x, 0.f);
    o.y = fmaxf(acc.y * inv + bv.y, 0.f);
    o.z = fmaxf(acc.z * inv + bv.z, 0.f);
    o.w = fmaxf(acc.w * inv + bv.w, 0.f);
    *(float4*)&out[(size_t)n * F1 + c] = o;
}

// ---------------- GEMM2: thread-per-(2 nodes, 8 classes), W2 staged once, fp16 fea2 out ----------------
#define G2N 102   // nodes per block: 51 pairs, 255 active threads
__global__ __launch_bounds__(256) void gemm2_k(const float* __restrict__ h1,
                                               const float* __restrict__ W2,
                                               const float* __restrict__ b2,
                                               const float* __restrict__ att2,
                                               __half* __restrict__ fea2h,
                                               float* __restrict__ s2I,
                                               float* __restrict__ s2J) {
    __shared__ float Ws[F1 * CLS];         // 40 KB
    __shared__ float redI[G2N][5];
    __shared__ float redJ[G2N][5];
    int tid = threadIdx.x;
    for (int i = tid * 4; i < F1 * CLS; i += 256 * 4)
        *(float4*)&Ws[i] = *(const float4*)&W2[i];
    __syncthreads();
    int nl = tid / 5, g = tid - nl * 5;    // nl 0..50, g 0..4
    int na = blockIdx.x * G2N + nl * 2;
    int nb = na + 1;
    bool actA = (tid < 255) && (na < NN);
    bool actB = (tid < 255) && (nb < NN);
    int c0 = g * 8;
    float accA[8] = {}, accB[8] = {};
    if (actA) {
        const float* rowA = h1 + (size_t)na * F1;
        const float* rowB = h1 + (size_t)(actB ? nb : na) * F1;
        for (int k = 0; k < F1; k += 4) {
            float4 ha = *(const float4*)&rowA[k];
            float4 hb = *(const float4*)&rowB[k];
            float a[4] = {ha.x, ha.y, ha.z, ha.w};
            float bl[4] = {hb.x, hb.y, hb.z, hb.w};
            #pragma unroll
            for (int kk = 0; kk < 4; ++kk) {
                float4 w0 = *(const float4*)&Ws[(k + kk) * CLS + c0];
                float4 w1 = *(const float4*)&Ws[(k + kk) * CLS + c0 + 4];
                accA[0] += a[kk] * w0.x; accA[1] += a[kk] * w0.y;
                accA[2] += a[kk] * w0.z; accA[3] += a[kk] * w0.w;
                accA[4] += a[kk] * w1.x; accA[5] += a[kk] * w1.y;
                accA[6] += a[kk] * w1.z; accA[7] += a[kk] * w1.w;
                accB[0] += bl[kk] * w0.x; accB[1] += bl[kk] * w0.y;
                accB[2] += bl[kk] * w0.z; accB[3] += bl[kk] * w0.w;
                accB[4] += bl[kk] * w1.x; accB[5] += bl[kk] * w1.y;
                accB[6] += bl[kk] * w1.z; accB[7] += bl[kk] * w1.w;
            }
        }
        float4 bb0 = *(const float4*)&b2[c0];
        float4 bb1 = *(const float4*)&b2[c0 + 4];
        float bias8[8] = {bb0.x, bb0.y, bb0.z, bb0.w, bb1.x, bb1.y, bb1.z, bb1.w};
        float sIa = 0.f, sJa = 0.f, sIb = 0.f, sJb = 0.f;
        #pragma unroll
        for (int j = 0; j < 8; ++j) {
            accA[j] += bias8[j];
            accB[j] += bias8[j];
            float aI = att2[c0 + j], aJ = att2[CLS + c0 + j];
            sIa += accA[j] * aI; sJa += accA[j] * aJ;
            sIb += accB[j] * aI; sJb += accB[j] * aJ;
        }
        H8 ha8;
        ha8.a = __floats2half2_rn(accA[0], accA[1]);
        ha8.b = __floats2half2_rn(accA[2], accA[3]);
        ha8.c = __floats2half2_rn(accA[4], accA[5]);
        ha8.d = __floats2half2_rn(accA[6], accA[7]);
        *(H8*)&fea2h[(size_t)na * CLS + c0] = ha8;
        redI[nl * 2][g] = sIa;
        redJ[nl * 2][g] = sJa;
        if (actB) {
            H8 hb8;
            hb8.a = __floats2half2_rn(accB[0], accB[1]);
            hb8.b = __floats2half2_rn(accB[2], accB[3]);
            hb8.c = __floats2half2_rn(accB[4], accB[5]);
            hb8.d = __floats2half2_rn(accB[6], accB[7]);
            *(H8*)&fea2h[(size_t)nb * CLS + c0] = hb8;
            redI[nl * 2 + 1][g] = sIb;
            redJ[nl * 2 + 1][g] = sJb;
        }
    }
    __syncthreads();
    if (actA && g == 0) {
        int r = nl * 2;
        s2I[na] = redI[r][0] + redI[r][1] + redI[r][2] + redI[r][3] + redI[r][4];
        s2J[na] = redJ[r][0] + redJ[r][1] + redJ[r][2] + redJ[r][3] + redJ[r][4];
        if (actB) {
            s2I[nb] = redI[r + 1][0] + redI[r + 1][1] + redI[r + 1][2] + redI[r + 1][3] + redI[r + 1][4];
            s2J[nb] = redJ[r + 1][0] + redJ[r + 1][1] + redJ[r + 1][2] + redJ[r + 1][3] + redJ[r + 1][4];
        }
    }
}

// ---------------- layer-2 aggregation + bias + row softmax (fp16 fea2 gathers) ----------------
__global__ __launch_bounds__(256) void agg2_k(const __half* __restrict__ fea2h,
                                              const float* __restrict__ s2I,
                                              const float* __restrict__ s2J,
                                              const int* __restrict__ row_off,
                                              const int* __restrict__ csr,
                                              const float* __restrict__ bias2,
                                              float* __restrict__ out) {
    int wid = threadIdx.x >> 6, lane = threadIdx.x & 63;
    int n = blockIdx.x * 4 + wid;
    if (n >= NN) return;
    float si = s2I[n], sjn = s2J[n];
    int c = lane < CLS ? lane : 0;
    float p = __expf(lrelu(si + sjn));
    float asum = p;
    float acc = __half2float(fea2h[(size_t)n * CLS + c]) * p;
    int beg = row_off[n], end = row_off[n + 1];
    int e = beg;
    for (; e + 8 <= end; e += 8) {
        int s0 = csr[e + 0], s1 = csr[e + 1], s2 = csr[e + 2], s3 = csr[e + 3];
        int s4 = csr[e + 4], s5 = csr[e + 5], s6 = csr[e + 6], s7 = csr[e + 7];
        float a0 = s2J[s0], a1 = s2J[s1], a2 = s2J[s2], a3 = s2J[s3];
        float a4 = s2J[s4], a5 = s2J[s5], a6 = s2J[s6], a7 = s2J[s7];
        __half f0 = fea2h[(size_t)s0 * CLS + c];
        __half f1 = fea2h[(size_t)s1 * CLS + c];
        __half f2 = fea2h[(size_t)s2 * CLS + c];
        __half f3 = fea2h[(size_t)s3 * CLS + c];
        __half f4 = fea2h[(size_t)s4 * CLS + c];
        __half f5 = fea2h[(size_t)s5 * CLS + c];
        __half f6 = fea2h[(size_t)s6 * CLS + c];
        __half f7 = fea2h[(size_t)s7 * CLS + c];
        float p0 = __expf(lrelu(si + a0));
        float p1 = __expf(lrelu(si + a1));
        float p2 = __expf(lrelu(si + a2));
        float p3 = __expf(lrelu(si + a3));
        float p4 = __expf(lrelu(si + a4));
        float p5 = __expf(lrelu(si + a5));
        float p6 = __expf(lrelu(si + a6));
        float p7 = __expf(lrelu(si + a7));
        asum += ((p0 + p1) + (p2 + p3)) + ((p4 + p5) + (p6 + p7));
        acc += (__half2float(f0) * p0 + __half2float(f1) * p1
              + __half2float(f2) * p2 + __half2float(f3) * p3)
             + (__half2float(f4) * p4 + __half2float(f5) * p5
              + __half2float(f6) * p6 + __half2float(f7) * p7);
    }
    for (; e + 4 <= end; e += 4) {
        int s0 = csr[e], s1 = csr[e + 1], s2 = csr[e + 2], s3 = csr[e + 3];
        float p0 = __expf(lrelu(si + s2J[s0]));
        float p1 = __expf(lrelu(si + s2J[s1]));
        float p2 = __expf(lrelu(si + s2J[s2]));
        float p3 = __expf(lrelu(si + s2J[s3]));
        __half f0 = fea2h[(size_t)s0 * CLS + c];
        __half f1 = fea2h[(size_t)s1 * CLS + c];
        __half f2 = fea2h[(size_t)s2 * CLS + c];
        __half f3 = fea2h[(size_t)s3 * CLS + c];
        asum += (p0 + p1) + (p2 + p3);
        acc += __half2float(f0) * p0 + __half2float(f1) * p1
             + __half2float(f2) * p2 + __half2float(f3) * p3;
    }
    for (; e < end; ++e) {
        int s = csr[e];
        float pe = __expf(lrelu(si + s2J[s]));
        asum += pe;
        acc += __half2float(fea2h[(size_t)s * CLS + c]) * pe;
    }
    float row = acc / (asum + 1e-16f) + bias2[c];
    float v = (lane < CLS) ? row : -3.0e38f;
    float vm = v;
    #pragma unroll
    for (int off = 32; off; off >>= 1) vm = fmaxf(vm, __shfl_xor(vm, off));
    float ex = (lane < CLS) ? __expf(v - vm) : 0.f;
    float es = ex;
    #pragma unroll
    for (int off = 32; off; off >>= 1) es += __shfl_xor(es, off);
    if (lane < CLS) out[(size_t)n * CLS + lane] = ex / es;
}

extern "C" void kernel_launch(void* const* d_in, const int* in_sizes, int n_in,
                              void* d_out, int out_size, void* d_ws, size_t ws_size,
                              hipStream_t stream) {
    const float* x     = (const float*)d_in[0];
    const int*   ei    = (const int*)d_in[1];
    const float* w1    = (const float*)d_in[2];
    const float* b1    = (const float*)d_in[3];
    const float* att1  = (const float*)d_in[4];
    const float* bias1 = (const float*)d_in[5];
    const float* w2    = (const float*)d_in[6];
    const float* b2    = (const float*)d_in[7];
    const float* att2  = (const float*)d_in[8];
    const float* bias2 = (const float*)d_in[9];
    const int* src = ei;
    const int* dst = ei + NE;
    float* out = (float*)d_out;

    char* p = (char*)d_ws;
    auto alloc = [&](size_t bytes) {
        char* r = p;
        p += (bytes + 255) & ~(size_t)255;
        return r;
    };
    __half* fea1h = (__half*)alloc((size_t)NN * F1 * 2);
    float* h1     = (float*)alloc((size_t)NN * F1 * 4);
    float* sI1    = (float*)alloc((size_t)NN * 4 * 4);
    float* sJ1    = (float*)alloc((size_t)NN * 4 * 4);
    __half* fea2h = (__half*)alloc((size_t)NN * CLS * 2);
    float* s2I    = (float*)alloc((size_t)NN * 4);
    float* s2J    = (float*)alloc((size_t)NN * 4);
    int*   deg    = (int*)alloc((size_t)NN * 4);
    int*   row_off= (int*)alloc((size_t)(NN + 1) * 4);
    int*   bsum   = (int*)alloc((size_t)NB * 4);
    int*   bpref  = (int*)alloc((size_t)NB * 4);
    int*   ord    = (int*)alloc((size_t)NE * 4);
    int*   csr    = (int*)alloc((size_t)NE * 4);
    float* ep1    = (float*)alloc((size_t)NE * 4 * 4);

    hipMemsetAsync(deg, 0, (size_t)NN * 4, stream);

    dim3 g1((NN + BM - 1) / BM, F1 / BN2);
    gemm1_k<<<g1, 256, 0, stream>>>(x, w1, b1, att1, fea1h, sI1, sJ1);
    hist_k<<<(NE + 255) / 256, 256, 0, stream>>>(dst, deg, ord);
    scan1_k<<<NB, 1024, 0, stream>>>(deg, row_off, bsum);
    scan2_k<<<1, 64, 0, stream>>>(bsum, bpref);
    scan3_k<<<NB, 1024, 0, stream>>>(row_off, bpref);
    scatter_k<<<(NE + 255) / 256, 256, 0, stream>>>(src, dst, ord, row_off,
                                                    sI1, sJ1, csr, (float4*)ep1);
    agg1_k<<<(NN + 3) / 4, 256, 0, stream>>>(fea1h, sI1, sJ1, ep1, row_off, csr, bias1, h1);
    gemm2_k<<<(NN + G2N - 1) / G2N, 256, 0, stream>>>(h1, w2, b2, att2, fea2h, s2I, s2J);
    agg2_k<<<(NN + 3) / 4, 256, 0, stream>>>(fea2h, s2I, s2J, row_off, csr, bias2, out);
}

// Round 12
// 228.353 us; speedup vs baseline: 1.1348x; 1.1348x over previous
//
#include <hip/hip_runtime.h>
#include <hip/hip_fp16.h>

#define NN 50000
#define NE 800000
#define INFEAT 128
#define F1 256
#define HID 64
#define CLS 40
#define NEGS 0.2f
#define NB 49   // ceil(NN / 1024)

__device__ __forceinline__ float lrelu(float x) { return x > 0.0f ? x : NEGS * x; }

struct alignas(8) H4 { __half2 a, b; };
struct alignas(16) H8 { __half2 a, b, c, d; };

typedef __attribute__((ext_vector_type(8))) _Float16 f16x8;
typedef __attribute__((ext_vector_type(4))) float f32x4;

// ---------------- GEMM1 via MFMA fp16: fea1h = fp16(x @ W1 + b1), fused scores ----------------
// block = 256 thr (4 waves), tile 128 rows x 64 cols (one head), K-steps of 32.
// Per wave: 32 rows x 64 cols = 2x4 grid of 16x16 MFMA tiles.
#define GBM 128
__global__ __launch_bounds__(256) void gemm1_k(const float* __restrict__ A,
                                               const float* __restrict__ W,
                                               const float* __restrict__ b,
                                               const float* __restrict__ att1,
                                               __half* __restrict__ feah,
                                               float* __restrict__ sI,
                                               float* __restrict__ sJ) {
    // fp16 LDS tiles, row stride 40 (80 B): bank walk period 8 -> 2-way (free)
    __shared__ __align__(16) _Float16 As[128][40];   // As[row][k]
    __shared__ __align__(16) _Float16 Ws[64][40];    // Ws[col][k] (transposed W)
    int tid = threadIdx.x;
    int wid = tid >> 6, lane = tid & 63;
    int row0 = blockIdx.x * GBM;
    int head = blockIdx.y;
    int colB = head * 64;
    int lr = lane & 15;          // row/col within 16-tile
    int lg = lane >> 4;          // k-group / output row group

    f32x4 acc[2][4];
    #pragma unroll
    for (int rt = 0; rt < 2; ++rt)
        #pragma unroll
        for (int ct = 0; ct < 4; ++ct) acc[rt][ct] = (f32x4){0.f, 0.f, 0.f, 0.f};

    int wcol = tid & 63;         // W staging: column
    int wkg  = tid >> 6;         // W staging: k-group 0..3

    for (int k0 = 0; k0 < INFEAT; k0 += 32) {
        // stage A tile 128x32 (f32 -> fp16): 1024 float4 chunks / 256 threads
        #pragma unroll
        for (int i = 0; i < 4; ++i) {
            int q = tid + 256 * i;
            int r = q >> 3;              // 0..127
            int c4 = (q & 7) * 4;        // 0..28
            int grow = row0 + r;
            float4 v = make_float4(0.f, 0.f, 0.f, 0.f);
            if (grow < NN) v = *(const float4*)&A[(size_t)grow * INFEAT + k0 + c4];
            As[r][c4 + 0] = (_Float16)v.x; As[r][c4 + 1] = (_Float16)v.y;
            As[r][c4 + 2] = (_Float16)v.z; As[r][c4 + 3] = (_Float16)v.w;
        }
        // stage W tile transposed 64 cols x 32 k (f32 -> fp16), one b128 write per thread
        {
            f16x8 wv;
            #pragma unroll
            for (int j = 0; j < 8; ++j)
                wv[j] = (_Float16)W[(size_t)(k0 + wkg * 8 + j) * F1 + colB + wcol];
            *(f16x8*)&Ws[wcol][wkg * 8] = wv;
        }
        __syncthreads();
        f16x8 afrag[2], bfrag[4];
        #pragma unroll
        for (int rt = 0; rt < 2; ++rt)
            afrag[rt] = *(const f16x8*)&As[wid * 32 + rt * 16 + lr][lg * 8];
        #pragma unroll
        for (int ct = 0; ct < 4; ++ct)
            bfrag[ct] = *(const f16x8*)&Ws[ct * 16 + lr][lg * 8];
        #pragma unroll
        for (int rt = 0; rt < 2; ++rt)
            #pragma unroll
            for (int ct = 0; ct < 4; ++ct)
                acc[rt][ct] = __builtin_amdgcn_mfma_f32_16x16x32_f16(
                    afrag[rt], bfrag[ct], acc[rt][ct], 0, 0, 0);
        __syncthreads();
    }
    // epilogue: bias + fp16 store + fused per-head scores
    float aIv[4], aJv[4], bv[4];
    #pragma unroll
    for (int ct = 0; ct < 4; ++ct) {
        int cin = ct * 16 + lr;
        aIv[ct] = att1[head * 2 * HID + cin];
        aJv[ct] = att1[head * 2 * HID + HID + cin];
        bv[ct]  = b[colB + cin];
    }
    #pragma unroll
    for (int rt = 0; rt < 2; ++rt) {
        #pragma unroll
        for (int i = 0; i < 4; ++i) {
            int grow = row0 + wid * 32 + rt * 16 + lg * 4 + i;
            float o[4];
            float sIp = 0.f, sJp = 0.f;
            #pragma unroll
            for (int ct = 0; ct < 4; ++ct) {
                o[ct] = acc[rt][ct][i] + bv[ct];
                sIp += o[ct] * aIv[ct];
                sJp += o[ct] * aJv[ct];
            }
            #pragma unroll
            for (int off = 1; off < 16; off <<= 1) {
                sIp += __shfl_xor(sIp, off);
                sJp += __shfl_xor(sJp, off);
            }
            if (grow < NN) {
                #pragma unroll
                for (int ct = 0; ct < 4; ++ct)
                    feah[(size_t)grow * F1 + colB + ct * 16 + lr] = __float2half(o[ct]);
                if (lr == 0) {
                    sI[grow * 4 + head] = sIp;
                    sJ[grow * 4 + head] = sJp;
                }
            }
        }
    }
}

// ---------------- CSR build: histogram harvests the ordinal ----------------
__global__ void hist_k(const int* __restrict__ dst, int* __restrict__ deg,
                       int* __restrict__ ord) {
    int e = blockIdx.x * blockDim.x + threadIdx.x;
    if (e < NE) ord[e] = atomicAdd(&deg[dst[e]], 1);
}

// hierarchical scan: 49 blocks of 1024, then 1-wave scan of block sums, then add-back
__global__ __launch_bounds__(1024) void scan1_k(const int* __restrict__ deg,
                                                int* __restrict__ row_off,
                                                int* __restrict__ bsum) {
    __shared__ int tmp[1024];
    int tid = threadIdx.x;
    int gid = blockIdx.x * 1024 + tid;
    int v = (gid < NN) ? deg[gid] : 0;
    tmp[tid] = v;
    __syncthreads();
    #pragma unroll
    for (int off = 1; off < 1024; off <<= 1) {
        int t = (tid >= off) ? tmp[tid - off] : 0;
        __syncthreads();
        tmp[tid] += t;
        __syncthreads();
    }
    if (gid < NN) row_off[gid] = tmp[tid] - v;   // exclusive
    if (tid == 1023) bsum[blockIdx.x] = tmp[1023];
}

__global__ void scan2_k(const int* __restrict__ bsum, int* __restrict__ bpref) {
    int tid = threadIdx.x;           // 64 threads, one wave
    int orig = (tid < NB) ? bsum[tid] : 0;
    int v = orig;
    #pragma unroll
    for (int off = 1; off < 64; off <<= 1) {
        int t = __shfl_up(v, off);
        if (tid >= off) v += t;
    }
    if (tid < NB) bpref[tid] = v - orig;   // exclusive block prefix
}

__global__ __launch_bounds__(1024) void scan3_k(int* __restrict__ row_off,
                                                const int* __restrict__ bpref) {
    int gid = blockIdx.x * 1024 + threadIdx.x;
    if (gid < NN) row_off[gid] += bpref[blockIdx.x];
    if (gid == 0) row_off[NN] = NE;      // total degree is exactly NE
}

// ---------------- scatter: atomic-free (pos = row_off[dst] + ord), fused ep1 ----------------
__global__ void scatter_k(const int* __restrict__ src, const int* __restrict__ dst,
                          const int* __restrict__ ord, const int* __restrict__ row_off,
                          const float* __restrict__ sI, const float* __restrict__ sJ,
                          int* __restrict__ csr, float4* __restrict__ ep4) {
    int e = blockIdx.x * blockDim.x + threadIdx.x;
    if (e >= NE) return;
    int s = src[e], d = dst[e];
    int pos = row_off[d] + ord[e];
    float4 si = *(const float4*)&sI[d * 4];
    float4 sj = *(const float4*)&sJ[s * 4];
    float4 r;
    r.x = __expf(lrelu(si.x + sj.x));
    r.y = __expf(lrelu(si.y + sj.y));
    r.z = __expf(lrelu(si.z + sj.z));
    r.w = __expf(lrelu(si.w + sj.w));
    csr[pos] = s;
    ep4[pos] = r;
}

// ---------------- layer-1 aggregation: streams precomputed ep, fp16 row gathers ----------------
__global__ __launch_bounds__(256, 6) void agg1_k(const __half* __restrict__ feah,
                                                 const float* __restrict__ sI,
                                                 const float* __restrict__ sJ,
                                                 const float* __restrict__ epf,
                                                 const int* __restrict__ row_off,
                                                 const int* __restrict__ csr,
                                                 const float* __restrict__ bias,
                                                 float* __restrict__ out) {
    int wid = threadIdx.x >> 6, lane = threadIdx.x & 63;
    int n = blockIdx.x * 4 + wid;
    if (n >= NN) return;
    int h = lane >> 4;           // head of this lane's channels
    int c = lane * 4;            // channel group
    // self loop
    float p = __expf(lrelu(sI[n * 4 + h] + sJ[n * 4 + h]));
    float asum = p;
    H4 vs = *(const H4*)&feah[(size_t)n * F1 + c];
    float2 sx = __half22float2(vs.a), sy = __half22float2(vs.b);
    float4 acc = make_float4(sx.x * p, sx.y * p, sy.x * p, sy.y * p);
    int beg = row_off[n], end = row_off[n + 1];
    int e = beg;
    for (; e + 8 <= end; e += 8) {
        int s0 = csr[e + 0], s1 = csr[e + 1], s2 = csr[e + 2], s3 = csr[e + 3];
        int s4 = csr[e + 4], s5 = csr[e + 5], s6 = csr[e + 6], s7 = csr[e + 7];
        float p0 = epf[(e + 0) * 4 + h], p1 = epf[(e + 1) * 4 + h];
        float p2 = epf[(e + 2) * 4 + h], p3 = epf[(e + 3) * 4 + h];
        float p4 = epf[(e + 4) * 4 + h], p5 = epf[(e + 5) * 4 + h];
        float p6 = epf[(e + 6) * 4 + h], p7 = epf[(e + 7) * 4 + h];
        H4 v0 = *(const H4*)&feah[(size_t)s0 * F1 + c];
        H4 v1 = *(const H4*)&feah[(size_t)s1 * F1 + c];
        H4 v2 = *(const H4*)&feah[(size_t)s2 * F1 + c];
        H4 v3 = *(const H4*)&feah[(size_t)s3 * F1 + c];
        H4 v4 = *(const H4*)&feah[(size_t)s4 * F1 + c];
        H4 v5 = *(const H4*)&feah[(size_t)s5 * F1 + c];
        H4 v6 = *(const H4*)&feah[(size_t)s6 * F1 + c];
        H4 v7 = *(const H4*)&feah[(size_t)s7 * F1 + c];
        asum += ((p0 + p1) + (p2 + p3)) + ((p4 + p5) + (p6 + p7));
        float2 x0 = __half22float2(v0.a), y0 = __half22float2(v0.b);
        float2 x1 = __half22float2(v1.a), y1 = __half22float2(v1.b);
        float2 x2 = __half22float2(v2.a), y2 = __half22float2(v2.b);
        float2 x3 = __half22float2(v3.a), y3 = __half22float2(v3.b);
        float2 x4 = __half22float2(v4.a), y4 = __half22float2(v4.b);
        float2 x5 = __half22float2(v5.a), y5 = __half22float2(v5.b);
        float2 x6 = __half22float2(v6.a), y6 = __half22float2(v6.b);
        float2 x7 = __half22float2(v7.a), y7 = __half22float2(v7.b);
        acc.x += (x0.x * p0 + x1.x * p1 + x2.x * p2 + x3.x * p3)
               + (x4.x * p4 + x5.x * p5 + x6.x * p6 + x7.x * p7);
        acc.y += (x0.y * p0 + x1.y * p1 + x2.y * p2 + x3.y * p3)
               + (x4.y * p4 + x5.y * p5 + x6.y * p6 + x7.y * p7);
        acc.z += (y0.x * p0 + y1.x * p1 + y2.x * p2 + y3.x * p3)
               + (y4.x * p4 + y5.x * p5 + y6.x * p6 + y7.x * p7);
        acc.w += (y0.y * p0 + y1.y * p1 + y2.y * p2 + y3.y * p3)
               + (y4.y * p4 + y5.y * p5 + y6.y * p6 + y7.y * p7);
    }
    for (; e + 4 <= end; e += 4) {
        int s0 = csr[e], s1 = csr[e + 1], s2 = csr[e + 2], s3 = csr[e + 3];
        float p0 = epf[(e + 0) * 4 + h], p1 = epf[(e + 1) * 4 + h];
        float p2 = epf[(e + 2) * 4 + h], p3 = epf[(e + 3) * 4 + h];
        H4 v0 = *(const H4*)&feah[(size_t)s0 * F1 + c];
        H4 v1 = *(const H4*)&feah[(size_t)s1 * F1 + c];
        H4 v2 = *(const H4*)&feah[(size_t)s2 * F1 + c];
        H4 v3 = *(const H4*)&feah[(size_t)s3 * F1 + c];
        asum += (p0 + p1) + (p2 + p3);
        float2 x0 = __half22float2(v0.a), y0 = __half22float2(v0.b);
        float2 x1 = __half22float2(v1.a), y1 = __half22float2(v1.b);
        float2 x2 = __half22float2(v2.a), y2 = __half22float2(v2.b);
        float2 x3 = __half22float2(v3.a), y3 = __half22float2(v3.b);
        acc.x += x0.x * p0 + x1.x * p1 + x2.x * p2 + x3.x * p3;
        acc.y += x0.y * p0 + x1.y * p1 + x2.y * p2 + x3.y * p3;
        acc.z += y0.x * p0 + y1.x * p1 + y2.x * p2 + y3.x * p3;
        acc.w += y0.y * p0 + y1.y * p1 + y2.y * p2 + y3.y * p3;
    }
    for (; e < end; ++e) {
        int s = csr[e];
        float pe = epf[e * 4 + h];
        asum += pe;
        H4 v = *(const H4*)&feah[(size_t)s * F1 + c];
        float2 x = __half22float2(v.a), y = __half22float2(v.b);
        acc.x += x.x * pe; acc.y += x.y * pe;
        acc.z += y.x * pe; acc.w += y.y * pe;
    }
    float inv = 1.0f / (asum + 1e-16f);
    float4 bv = *(const float4*)&bias[c];
    float4 o;
    o.x = fmaxf(acc.x * inv + bv.x, 0.f);
    o.y = fmaxf(acc.y * inv + bv.y, 0.f);
    o.z = fmaxf(acc.z * inv + bv.z, 0.f);
    o.w = fmaxf(acc.w * inv + bv.w, 0.f);
    *(float4*)&out[(size_t)n * F1 + c] = o;
}

// ---------------- GEMM2: thread-per-(2 nodes, 8 classes), W2 staged once, fp16 fea2 out ----------------
#define G2N 102   // nodes per block: 51 pairs, 255 active threads
__global__ __launch_bounds__(256) void gemm2_k(const float* __restrict__ h1,
                                               const float* __restrict__ W2,
                                               const float* __restrict__ b2,
                                               const float* __restrict__ att2,
                                               __half* __restrict__ fea2h,
                                               float* __restrict__ s2I,
                                               float* __restrict__ s2J) {
    __shared__ float Ws[F1 * CLS];         // 40 KB
    __shared__ float redI[G2N][5];
    __shared__ float redJ[G2N][5];
    int tid = threadIdx.x;
    for (int i = tid * 4; i < F1 * CLS; i += 256 * 4)
        *(float4*)&Ws[i] = *(const float4*)&W2[i];
    __syncthreads();
    int nl = tid / 5, g = tid - nl * 5;    // nl 0..50, g 0..4
    int na = blockIdx.x * G2N + nl * 2;
    int nb = na + 1;
    bool actA = (tid < 255) && (na < NN);
    bool actB = (tid < 255) && (nb < NN);
    int c0 = g * 8;
    float accA[8] = {}, accB[8] = {};
    if (actA) {
        const float* rowA = h1 + (size_t)na * F1;
        const float* rowB = h1 + (size_t)(actB ? nb : na) * F1;
        for (int k = 0; k < F1; k += 4) {
            float4 ha = *(const float4*)&rowA[k];
            float4 hb = *(const float4*)&rowB[k];
            float a[4] = {ha.x, ha.y, ha.z, ha.w};
            float bl[4] = {hb.x, hb.y, hb.z, hb.w};
            #pragma unroll
            for (int kk = 0; kk < 4; ++kk) {
                float4 w0 = *(const float4*)&Ws[(k + kk) * CLS + c0];
                float4 w1 = *(const float4*)&Ws[(k + kk) * CLS + c0 + 4];
                accA[0] += a[kk] * w0.x; accA[1] += a[kk] * w0.y;
                accA[2] += a[kk] * w0.z; accA[3] += a[kk] * w0.w;
                accA[4] += a[kk] * w1.x; accA[5] += a[kk] * w1.y;
                accA[6] += a[kk] * w1.z; accA[7] += a[kk] * w1.w;
                accB[0] += bl[kk] * w0.x; accB[1] += bl[kk] * w0.y;
                accB[2] += bl[kk] * w0.z; accB[3] += bl[kk] * w0.w;
                accB[4] += bl[kk] * w1.x; accB[5] += bl[kk] * w1.y;
                accB[6] += bl[kk] * w1.z; accB[7] += bl[kk] * w1.w;
            }
        }
        float4 bb0 = *(const float4*)&b2[c0];
        float4 bb1 = *(const float4*)&b2[c0 + 4];
        float bias8[8] = {bb0.x, bb0.y, bb0.z, bb0.w, bb1.x, bb1.y, bb1.z, bb1.w};
        float sIa = 0.f, sJa = 0.f, sIb = 0.f, sJb = 0.f;
        #pragma unroll
        for (int j = 0; j < 8; ++j) {
            accA[j] += bias8[j];
            accB[j] += bias8[j];
            float aI = att2[c0 + j], aJ = att2[CLS + c0 + j];
            sIa += accA[j] * aI; sJa += accA[j] * aJ;
            sIb += accB[j] * aI; sJb += accB[j] * aJ;
        }
        H8 ha8;
        ha8.a = __floats2half2_rn(accA[0], accA[1]);
        ha8.b = __floats2half2_rn(accA[2], accA[3]);
        ha8.c = __floats2half2_rn(accA[4], accA[5]);
        ha8.d = __floats2half2_rn(accA[6], accA[7]);
        *(H8*)&fea2h[(size_t)na * CLS + c0] = ha8;
        redI[nl * 2][g] = sIa;
        redJ[nl * 2][g] = sJa;
        if (actB) {
            H8 hb8;
            hb8.a = __floats2half2_rn(accB[0], accB[1]);
            hb8.b = __floats2half2_rn(accB[2], accB[3]);
            hb8.c = __floats2half2_rn(accB[4], accB[5]);
            hb8.d = __floats2half2_rn(accB[6], accB[7]);
            *(H8*)&fea2h[(size_t)nb * CLS + c0] = hb8;
            redI[nl * 2 + 1][g] = sIb;
            redJ[nl * 2 + 1][g] = sJb;
        }
    }
    __syncthreads();
    if (actA && g == 0) {
        int r = nl * 2;
        s2I[na] = redI[r][0] + redI[r][1] + redI[r][2] + redI[r][3] + redI[r][4];
        s2J[na] = redJ[r][0] + redJ[r][1] + redJ[r][2] + redJ[r][3] + redJ[r][4];
        if (actB) {
            s2I[nb] = redI[r + 1][0] + redI[r + 1][1] + redI[r + 1][2] + redI[r + 1][3] + redI[r + 1][4];
            s2J[nb] = redJ[r + 1][0] + redJ[r + 1][1] + redJ[r + 1][2] + redJ[r + 1][3] + redJ[r + 1][4];
        }
    }
}

// ---------------- layer-2 aggregation + bias + row softmax (fp16 fea2 gathers) ----------------
__global__ __launch_bounds__(256) void agg2_k(const __half* __restrict__ fea2h,
                                              const float* __restrict__ s2I,
                                              const float* __restrict__ s2J,
                                              const int* __restrict__ row_off,
                                              const int* __restrict__ csr,
                                              const float* __restrict__ bias2,
                                              float* __restrict__ out) {
    int wid = threadIdx.x >> 6, lane = threadIdx.x & 63;
    int n = blockIdx.x * 4 + wid;
    if (n >= NN) return;
    float si = s2I[n], sjn = s2J[n];
    int c = lane < CLS ? lane : 0;
    float p = __expf(lrelu(si + sjn));
    float asum = p;
    float acc = __half2float(fea2h[(size_t)n * CLS + c]) * p;
    int beg = row_off[n], end = row_off[n + 1];
    int e = beg;
    for (; e + 8 <= end; e += 8) {
        int s0 = csr[e + 0], s1 = csr[e + 1], s2 = csr[e + 2], s3 = csr[e + 3];
        int s4 = csr[e + 4], s5 = csr[e + 5], s6 = csr[e + 6], s7 = csr[e + 7];
        float a0 = s2J[s0], a1 = s2J[s1], a2 = s2J[s2], a3 = s2J[s3];
        float a4 = s2J[s4], a5 = s2J[s5], a6 = s2J[s6], a7 = s2J[s7];
        __half f0 = fea2h[(size_t)s0 * CLS + c];
        __half f1 = fea2h[(size_t)s1 * CLS + c];
        __half f2 = fea2h[(size_t)s2 * CLS + c];
        __half f3 = fea2h[(size_t)s3 * CLS + c];
        __half f4 = fea2h[(size_t)s4 * CLS + c];
        __half f5 = fea2h[(size_t)s5 * CLS + c];
        __half f6 = fea2h[(size_t)s6 * CLS + c];
        __half f7 = fea2h[(size_t)s7 * CLS + c];
        float p0 = __expf(lrelu(si + a0));
        float p1 = __expf(lrelu(si + a1));
        float p2 = __expf(lrelu(si + a2));
        float p3 = __expf(lrelu(si + a3));
        float p4 = __expf(lrelu(si + a4));
        float p5 = __expf(lrelu(si + a5));
        float p6 = __expf(lrelu(si + a6));
        float p7 = __expf(lrelu(si + a7));
        asum += ((p0 + p1) + (p2 + p3)) + ((p4 + p5) + (p6 + p7));
        acc += (__half2float(f0) * p0 + __half2float(f1) * p1
              + __half2float(f2) * p2 + __half2float(f3) * p3)
             + (__half2float(f4) * p4 + __half2float(f5) * p5
              + __half2float(f6) * p6 + __half2float(f7) * p7);
    }
    for (; e + 4 <= end; e += 4) {
        int s0 = csr[e], s1 = csr[e + 1], s2 = csr[e + 2], s3 = csr[e + 3];
        float p0 = __expf(lrelu(si + s2J[s0]));
        float p1 = __expf(lrelu(si + s2J[s1]));
        float p2 = __expf(lrelu(si + s2J[s2]));
        float p3 = __expf(lrelu(si + s2J[s3]));
        __half f0 = fea2h[(size_t)s0 * CLS + c];
        __half f1 = fea2h[(size_t)s1 * CLS + c];
        __half f2 = fea2h[(size_t)s2 * CLS + c];
        __half f3 = fea2h[(size_t)s3 * CLS + c];
        asum += (p0 + p1) + (p2 + p3);
        acc += __half2float(f0) * p0 + __half2float(f1) * p1
             + __half2float(f2) * p2 + __half2float(f3) * p3;
    }
    for (; e < end; ++e) {
        int s = csr[e];
        float pe = __expf(lrelu(si + s2J[s]));
        asum += pe;
        acc += __half2float(fea2h[(size_t)s * CLS + c]) * pe;
    }
    float row = acc / (asum + 1e-16f) + bias2[c];
    float v = (lane < CLS) ? row : -3.0e38f;
    float vm = v;
    #pragma unroll
    for (int off = 32; off; off >>= 1) vm = fmaxf(vm, __shfl_xor(vm, off));
    float ex = (lane < CLS) ? __expf(v - vm) : 0.f;
    float es = ex;
    #pragma unroll
    for (int off = 32; off; off >>= 1) es += __shfl_xor(es, off);
    if (lane < CLS) out[(size_t)n * CLS + lane] = ex / es;
}

extern "C" void kernel_launch(void* const* d_in, const int* in_sizes, int n_in,
                              void* d_out, int out_size, void* d_ws, size_t ws_size,
                              hipStream_t stream) {
    const float* x     = (const float*)d_in[0];
    const int*   ei    = (const int*)d_in[1];
    const float* w1    = (const float*)d_in[2];
    const float* b1    = (const float*)d_in[3];
    const float* att1  = (const float*)d_in[4];
    const float* bias1 = (const float*)d_in[5];
    const float* w2    = (const float*)d_in[6];
    const float* b2    = (const float*)d_in[7];
    const float* att2  = (const float*)d_in[8];
    const float* bias2 = (const float*)d_in[9];
    const int* src = ei;
    const int* dst = ei + NE;
    float* out = (float*)d_out;

    char* p = (char*)d_ws;
    auto alloc = [&](size_t bytes) {
        char* r = p;
        p += (bytes + 255) & ~(size_t)255;
        return r;
    };
    __half* fea1h = (__half*)alloc((size_t)NN * F1 * 2);
    float* h1     = (float*)alloc((size_t)NN * F1 * 4);
    float* sI1    = (float*)alloc((size_t)NN * 4 * 4);
    float* sJ1    = (float*)alloc((size_t)NN * 4 * 4);
    __half* fea2h = (__half*)alloc((size_t)NN * CLS * 2);
    float* s2I    = (float*)alloc((size_t)NN * 4);
    float* s2J    = (float*)alloc((size_t)NN * 4);
    int*   deg    = (int*)alloc((size_t)NN * 4);
    int*   row_off= (int*)alloc((size_t)(NN + 1) * 4);
    int*   bsum   = (int*)alloc((size_t)NB * 4);
    int*   bpref  = (int*)alloc((size_t)NB * 4);
    int*   ord    = (int*)alloc((size_t)NE * 4);
    int*   csr    = (int*)alloc((size_t)NE * 4);
    float* ep1    = (float*)alloc((size_t)NE * 4 * 4);

    hipMemsetAsync(deg, 0, (size_t)NN * 4, stream);

    dim3 g1((NN + GBM - 1) / GBM, 4);
    gemm1_k<<<g1, 256, 0, stream>>>(x, w1, b1, att1, fea1h, sI1, sJ1);
    hist_k<<<(NE + 255) / 256, 256, 0, stream>>>(dst, deg, ord);
    scan1_k<<<NB, 1024, 0, stream>>>(deg, row_off, bsum);
    scan2_k<<<1, 64, 0, stream>>>(bsum, bpref);
    scan3_k<<<NB, 1024, 0, stream>>>(row_off, bpref);
    scatter_k<<<(NE + 255) / 256, 256, 0, stream>>>(src, dst, ord, row_off,
                                                    sI1, sJ1, csr, (float4*)ep1);
    agg1_k<<<(NN + 3) / 4, 256, 0, stream>>>(fea1h, sI1, sJ1, ep1, row_off, csr, bias1, h1);
    gemm2_k<<<(NN + G2N - 1) / G2N, 256, 0, stream>>>(h1, w2, b2, att2, fea2h, s2I, s2J);
    agg2_k<<<(NN + 3) / 4, 256, 0, stream>>>(fea2h, s2I, s2J, row_off, csr, bias2, out);
}

// Round 13
// 224.242 us; speedup vs baseline: 1.1556x; 1.0183x over previous
//
#include <hip/hip_runtime.h>
#include <hip/hip_fp16.h>

#define NN 50000
#define NE 800000
#define INFEAT 128
#define F1 256
#define HID 64
#define CLS 40
#define NEGS 0.2f
#define NB 49   // ceil(NN / 1024)

__device__ __forceinline__ float lrelu(float x) { return x > 0.0f ? x : NEGS * x; }

struct alignas(8) H4 { __half2 a, b; };
struct alignas(16) H8 { __half2 a, b, c, d; };

typedef __attribute__((ext_vector_type(8))) _Float16 f16x8;
typedef __attribute__((ext_vector_type(4))) float f32x4;

// ---------------- GEMM1 via MFMA fp16: fea1h = fp16(x @ W1 + b1), fused scores ----------------
#define GBM 128
__global__ __launch_bounds__(256) void gemm1_k(const float* __restrict__ A,
                                               const float* __restrict__ W,
                                               const float* __restrict__ b,
                                               const float* __restrict__ att1,
                                               __half* __restrict__ feah,
                                               float* __restrict__ sI,
                                               float* __restrict__ sJ) {
    __shared__ __align__(16) _Float16 As[128][40];
    __shared__ __align__(16) _Float16 Ws[64][40];
    int tid = threadIdx.x;
    int wid = tid >> 6, lane = tid & 63;
    int row0 = blockIdx.x * GBM;
    int head = blockIdx.y;
    int colB = head * 64;
    int lr = lane & 15;
    int lg = lane >> 4;

    f32x4 acc[2][4];
    #pragma unroll
    for (int rt = 0; rt < 2; ++rt)
        #pragma unroll
        for (int ct = 0; ct < 4; ++ct) acc[rt][ct] = (f32x4){0.f, 0.f, 0.f, 0.f};

    int wcol = tid & 63;
    int wkg  = tid >> 6;

    for (int k0 = 0; k0 < INFEAT; k0 += 32) {
        #pragma unroll
        for (int i = 0; i < 4; ++i) {
            int q = tid + 256 * i;
            int r = q >> 3;
            int c4 = (q & 7) * 4;
            int grow = row0 + r;
            float4 v = make_float4(0.f, 0.f, 0.f, 0.f);
            if (grow < NN) v = *(const float4*)&A[(size_t)grow * INFEAT + k0 + c4];
            As[r][c4 + 0] = (_Float16)v.x; As[r][c4 + 1] = (_Float16)v.y;
            As[r][c4 + 2] = (_Float16)v.z; As[r][c4 + 3] = (_Float16)v.w;
        }
        {
            f16x8 wv;
            #pragma unroll
            for (int j = 0; j < 8; ++j)
                wv[j] = (_Float16)W[(size_t)(k0 + wkg * 8 + j) * F1 + colB + wcol];
            *(f16x8*)&Ws[wcol][wkg * 8] = wv;
        }
        __syncthreads();
        f16x8 afrag[2], bfrag[4];
        #pragma unroll
        for (int rt = 0; rt < 2; ++rt)
            afrag[rt] = *(const f16x8*)&As[wid * 32 + rt * 16 + lr][lg * 8];
        #pragma unroll
        for (int ct = 0; ct < 4; ++ct)
            bfrag[ct] = *(const f16x8*)&Ws[ct * 16 + lr][lg * 8];
        #pragma unroll
        for (int rt = 0; rt < 2; ++rt)
            #pragma unroll
            for (int ct = 0; ct < 4; ++ct)
                acc[rt][ct] = __builtin_amdgcn_mfma_f32_16x16x32_f16(
                    afrag[rt], bfrag[ct], acc[rt][ct], 0, 0, 0);
        __syncthreads();
    }
    float aIv[4], aJv[4], bv[4];
    #pragma unroll
    for (int ct = 0; ct < 4; ++ct) {
        int cin = ct * 16 + lr;
        aIv[ct] = att1[head * 2 * HID + cin];
        aJv[ct] = att1[head * 2 * HID + HID + cin];
        bv[ct]  = b[colB + cin];
    }
    #pragma unroll
    for (int rt = 0; rt < 2; ++rt) {
        #pragma unroll
        for (int i = 0; i < 4; ++i) {
            int grow = row0 + wid * 32 + rt * 16 + lg * 4 + i;
            float o[4];
            float sIp = 0.f, sJp = 0.f;
            #pragma unroll
            for (int ct = 0; ct < 4; ++ct) {
                o[ct] = acc[rt][ct][i] + bv[ct];
                sIp += o[ct] * aIv[ct];
                sJp += o[ct] * aJv[ct];
            }
            #pragma unroll
            for (int off = 1; off < 16; off <<= 1) {
                sIp += __shfl_xor(sIp, off);
                sJp += __shfl_xor(sJp, off);
            }
            if (grow < NN) {
                #pragma unroll
                for (int ct = 0; ct < 4; ++ct)
                    feah[(size_t)grow * F1 + colB + ct * 16 + lr] = __float2half(o[ct]);
                if (lr == 0) {
                    sI[grow * 4 + head] = sIp;
                    sJ[grow * 4 + head] = sJp;
                }
            }
        }
    }
}

// ---------------- CSR build: histogram harvests the ordinal ----------------
__global__ void hist_k(const int* __restrict__ dst, int* __restrict__ deg,
                       int* __restrict__ ord) {
    int e = blockIdx.x * blockDim.x + threadIdx.x;
    if (e < NE) ord[e] = atomicAdd(&deg[dst[e]], 1);
}

__global__ __launch_bounds__(1024) void scan1_k(const int* __restrict__ deg,
                                                int* __restrict__ row_off,
                                                int* __restrict__ bsum) {
    __shared__ int tmp[1024];
    int tid = threadIdx.x;
    int gid = blockIdx.x * 1024 + tid;
    int v = (gid < NN) ? deg[gid] : 0;
    tmp[tid] = v;
    __syncthreads();
    #pragma unroll
    for (int off = 1; off < 1024; off <<= 1) {
        int t = (tid >= off) ? tmp[tid - off] : 0;
        __syncthreads();
        tmp[tid] += t;
        __syncthreads();
    }
    if (gid < NN) row_off[gid] = tmp[tid] - v;   // exclusive
    if (tid == 1023) bsum[blockIdx.x] = tmp[1023];
}

__global__ void scan2_k(const int* __restrict__ bsum, int* __restrict__ bpref) {
    int tid = threadIdx.x;
    int orig = (tid < NB) ? bsum[tid] : 0;
    int v = orig;
    #pragma unroll
    for (int off = 1; off < 64; off <<= 1) {
        int t = __shfl_up(v, off);
        if (tid >= off) v += t;
    }
    if (tid < NB) bpref[tid] = v - orig;
}

__global__ __launch_bounds__(1024) void scan3_k(int* __restrict__ row_off,
                                                const int* __restrict__ bpref) {
    int gid = blockIdx.x * 1024 + threadIdx.x;
    if (gid < NN) row_off[gid] += bpref[blockIdx.x];
    if (gid == 0) row_off[NN] = NE;
}

// ---------------- scatter: atomic-free, fused ep1 ----------------
__global__ void scatter_k(const int* __restrict__ src, const int* __restrict__ dst,
                          const int* __restrict__ ord, const int* __restrict__ row_off,
                          const float* __restrict__ sI, const float* __restrict__ sJ,
                          int* __restrict__ csr, float4* __restrict__ ep4) {
    int e = blockIdx.x * blockDim.x + threadIdx.x;
    if (e >= NE) return;
    int s = src[e], d = dst[e];
    int pos = row_off[d] + ord[e];
    float4 si = *(const float4*)&sI[d * 4];
    float4 sj = *(const float4*)&sJ[s * 4];
    float4 r;
    r.x = __expf(lrelu(si.x + sj.x));
    r.y = __expf(lrelu(si.y + sj.y));
    r.z = __expf(lrelu(si.z + sj.z));
    r.w = __expf(lrelu(si.w + sj.w));
    csr[pos] = s;
    ep4[pos] = r;
}

// ---------------- layer-1 aggregation: fp16 gathers, fp16 h1 output ----------------
__global__ __launch_bounds__(256, 6) void agg1_k(const __half* __restrict__ feah,
                                                 const float* __restrict__ sI,
                                                 const float* __restrict__ sJ,
                                                 const float* __restrict__ epf,
                                                 const int* __restrict__ row_off,
                                                 const int* __restrict__ csr,
                                                 const float* __restrict__ bias,
                                                 __half* __restrict__ out) {
    int wid = threadIdx.x >> 6, lane = threadIdx.x & 63;
    int n = blockIdx.x * 4 + wid;
    if (n >= NN) return;
    int h = lane >> 4;
    int c = lane * 4;
    float p = __expf(lrelu(sI[n * 4 + h] + sJ[n * 4 + h]));
    float asum = p;
    H4 vs = *(const H4*)&feah[(size_t)n * F1 + c];
    float2 sx = __half22float2(vs.a), sy = __half22float2(vs.b);
    float4 acc = make_float4(sx.x * p, sx.y * p, sy.x * p, sy.y * p);
    int beg = row_off[n], end = row_off[n + 1];
    int e = beg;
    for (; e + 8 <= end; e += 8) {
        int s0 = csr[e + 0], s1 = csr[e + 1], s2 = csr[e + 2], s3 = csr[e + 3];
        int s4 = csr[e + 4], s5 = csr[e + 5], s6 = csr[e + 6], s7 = csr[e + 7];
        float p0 = epf[(e + 0) * 4 + h], p1 = epf[(e + 1) * 4 + h];
        float p2 = epf[(e + 2) * 4 + h], p3 = epf[(e + 3) * 4 + h];
        float p4 = epf[(e + 4) * 4 + h], p5 = epf[(e + 5) * 4 + h];
        float p6 = epf[(e + 6) * 4 + h], p7 = epf[(e + 7) * 4 + h];
        H4 v0 = *(const H4*)&feah[(size_t)s0 * F1 + c];
        H4 v1 = *(const H4*)&feah[(size_t)s1 * F1 + c];
        H4 v2 = *(const H4*)&feah[(size_t)s2 * F1 + c];
        H4 v3 = *(const H4*)&feah[(size_t)s3 * F1 + c];
        H4 v4 = *(const H4*)&feah[(size_t)s4 * F1 + c];
        H4 v5 = *(const H4*)&feah[(size_t)s5 * F1 + c];
        H4 v6 = *(const H4*)&feah[(size_t)s6 * F1 + c];
        H4 v7 = *(const H4*)&feah[(size_t)s7 * F1 + c];
        asum += ((p0 + p1) + (p2 + p3)) + ((p4 + p5) + (p6 + p7));
        float2 x0 = __half22float2(v0.a), y0 = __half22float2(v0.b);
        float2 x1 = __half22float2(v1.a), y1 = __half22float2(v1.b);
        float2 x2 = __half22float2(v2.a), y2 = __half22float2(v2.b);
        float2 x3 = __half22float2(v3.a), y3 = __half22float2(v3.b);
        float2 x4 = __half22float2(v4.a), y4 = __half22float2(v4.b);
        float2 x5 = __half22float2(v5.a), y5 = __half22float2(v5.b);
        float2 x6 = __half22float2(v6.a), y6 = __half22float2(v6.b);
        float2 x7 = __half22float2(v7.a), y7 = __half22float2(v7.b);
        acc.x += (x0.x * p0 + x1.x * p1 + x2.x * p2 + x3.x * p3)
               + (x4.x * p4 + x5.x * p5 + x6.x * p6 + x7.x * p7);
        acc.y += (x0.y * p0 + x1.y * p1 + x2.y * p2 + x3.y * p3)
               + (x4.y * p4 + x5.y * p5 + x6.y * p6 + x7.y * p7);
        acc.z += (y0.x * p0 + y1.x * p1 + y2.x * p2 + y3.x * p3)
               + (y4.x * p4 + y5.x * p5 + y6.x * p6 + y7.x * p7);
        acc.w += (y0.y * p0 + y1.y * p1 + y2.y * p2 + y3.y * p3)
               + (y4.y * p4 + y5.y * p5 + y6.y * p6 + y7.y * p7);
    }
    for (; e + 4 <= end; e += 4) {
        int s0 = csr[e], s1 = csr[e + 1], s2 = csr[e + 2], s3 = csr[e + 3];
        float p0 = epf[(e + 0) * 4 + h], p1 = epf[(e + 1) * 4 + h];
        float p2 = epf[(e + 2) * 4 + h], p3 = epf[(e + 3) * 4 + h];
        H4 v0 = *(const H4*)&feah[(size_t)s0 * F1 + c];
        H4 v1 = *(const H4*)&feah[(size_t)s1 * F1 + c];
        H4 v2 = *(const H4*)&feah[(size_t)s2 * F1 + c];
        H4 v3 = *(const H4*)&feah[(size_t)s3 * F1 + c];
        asum += (p0 + p1) + (p2 + p3);
        float2 x0 = __half22float2(v0.a), y0 = __half22float2(v0.b);
        float2 x1 = __half22float2(v1.a), y1 = __half22float2(v1.b);
        float2 x2 = __half22float2(v2.a), y2 = __half22float2(v2.b);
        float2 x3 = __half22float2(v3.a), y3 = __half22float2(v3.b);
        acc.x += x0.x * p0 + x1.x * p1 + x2.x * p2 + x3.x * p3;
        acc.y += x0.y * p0 + x1.y * p1 + x2.y * p2 + x3.y * p3;
        acc.z += y0.x * p0 + y1.x * p1 + y2.x * p2 + y3.x * p3;
        acc.w += y0.y * p0 + y1.y * p1 + y2.y * p2 + y3.y * p3;
    }
    for (; e < end; ++e) {
        int s = csr[e];
        float pe = epf[e * 4 + h];
        asum += pe;
        H4 v = *(const H4*)&feah[(size_t)s * F1 + c];
        float2 x = __half22float2(v.a), y = __half22float2(v.b);
        acc.x += x.x * pe; acc.y += x.y * pe;
        acc.z += y.x * pe; acc.w += y.y * pe;
    }
    float inv = 1.0f / (asum + 1e-16f);
    float4 bv = *(const float4*)&bias[c];
    H4 o4;
    o4.a = __floats2half2_rn(fmaxf(acc.x * inv + bv.x, 0.f),
                             fmaxf(acc.y * inv + bv.y, 0.f));
    o4.b = __floats2half2_rn(fmaxf(acc.z * inv + bv.z, 0.f),
                             fmaxf(acc.w * inv + bv.w, 0.f));
    *(H4*)&out[(size_t)n * F1 + c] = o4;
}

// ---------------- GEMM2 via MFMA fp16: fea2h = fp16(h1 @ W2 + b2), fused att2 scores ----------------
#define G2M 128
__global__ __launch_bounds__(256) void gemm2_k(const __half* __restrict__ h1h,
                                               const float* __restrict__ W2,
                                               const float* __restrict__ b2,
                                               const float* __restrict__ att2,
                                               __half* __restrict__ fea2h,
                                               float* __restrict__ s2I,
                                               float* __restrict__ s2J) {
    __shared__ __align__(16) _Float16 Ws2[48][264];  // [col][k], cols 40..47 zero
    __shared__ __align__(16) _Float16 As2[128][40];
    int tid = threadIdx.x;
    int wid = tid >> 6, lane = tid & 63;
    int lr = lane & 15, lg = lane >> 4;
    int row0 = blockIdx.x * G2M;
    // stage W2 transposed fp16 (once)
    for (int q = tid; q < 48 * 32; q += 256) {
        int col = q >> 5;
        int kg  = q & 31;
        f16x8 wv;
        #pragma unroll
        for (int j = 0; j < 8; ++j) {
            int k = kg * 8 + j;
            wv[j] = (col < CLS) ? (_Float16)W2[(size_t)k * CLS + col] : (_Float16)0.f;
        }
        *(f16x8*)&Ws2[col][kg * 8] = wv;
    }
    f32x4 acc[2][3];
    #pragma unroll
    for (int rt = 0; rt < 2; ++rt)
        #pragma unroll
        for (int ct = 0; ct < 3; ++ct) acc[rt][ct] = (f32x4){0.f, 0.f, 0.f, 0.f};

    for (int k0 = 0; k0 < F1; k0 += 32) {
        #pragma unroll
        for (int i = 0; i < 2; ++i) {
            int q = tid + 256 * i;
            int r = q >> 2;
            int c8 = (q & 3) * 8;
            int grow = row0 + r;
            f16x8 v;
            if (grow < NN) v = *(const f16x8*)&h1h[(size_t)grow * F1 + k0 + c8];
            else {
                #pragma unroll
                for (int j = 0; j < 8; ++j) v[j] = (_Float16)0.f;
            }
            *(f16x8*)&As2[r][c8] = v;
        }
        __syncthreads();
        f16x8 af[2], bf[3];
        #pragma unroll
        for (int rt = 0; rt < 2; ++rt)
            af[rt] = *(const f16x8*)&As2[wid * 32 + rt * 16 + lr][lg * 8];
        #pragma unroll
        for (int ct = 0; ct < 3; ++ct)
            bf[ct] = *(const f16x8*)&Ws2[ct * 16 + lr][k0 + lg * 8];
        #pragma unroll
        for (int rt = 0; rt < 2; ++rt)
            #pragma unroll
            for (int ct = 0; ct < 3; ++ct)
                acc[rt][ct] = __builtin_amdgcn_mfma_f32_16x16x32_f16(
                    af[rt], bf[ct], acc[rt][ct], 0, 0, 0);
        __syncthreads();
    }
    // epilogue: bias + fp16 store + fused scores
    float bcol[3], aIc[3], aJc[3];
    bool valid[3];
    #pragma unroll
    for (int ct = 0; ct < 3; ++ct) {
        int col = ct * 16 + lr;
        valid[ct] = col < CLS;
        int cc = valid[ct] ? col : 0;
        bcol[ct] = b2[cc];
        aIc[ct] = valid[ct] ? att2[cc] : 0.f;
        aJc[ct] = valid[ct] ? att2[CLS + cc] : 0.f;
    }
    #pragma unroll
    for (int rt = 0; rt < 2; ++rt) {
        #pragma unroll
        for (int i = 0; i < 4; ++i) {
            int grow = row0 + wid * 32 + rt * 16 + lg * 4 + i;
            float o[3];
            float sIp = 0.f, sJp = 0.f;
            #pragma unroll
            for (int ct = 0; ct < 3; ++ct) {
                o[ct] = acc[rt][ct][i] + bcol[ct];
                sIp += o[ct] * aIc[ct];
                sJp += o[ct] * aJc[ct];
            }
            #pragma unroll
            for (int off = 1; off < 16; off <<= 1) {
                sIp += __shfl_xor(sIp, off);
                sJp += __shfl_xor(sJp, off);
            }
            if (grow < NN) {
                #pragma unroll
                for (int ct = 0; ct < 3; ++ct)
                    if (valid[ct])
                        fea2h[(size_t)grow * CLS + ct * 16 + lr] = __float2half(o[ct]);
                if (lr == 0) {
                    s2I[grow] = sIp;
                    s2J[grow] = sJp;
                }
            }
        }
    }
}

// ---------------- layer-2 aggregation + bias + row softmax (fp16 fea2 gathers) ----------------
__global__ __launch_bounds__(256) void agg2_k(const __half* __restrict__ fea2h,
                                              const float* __restrict__ s2I,
                                              const float* __restrict__ s2J,
                                              const int* __restrict__ row_off,
                                              const int* __restrict__ csr,
                                              const float* __restrict__ bias2,
                                              float* __restrict__ out) {
    int wid = threadIdx.x >> 6, lane = threadIdx.x & 63;
    int n = blockIdx.x * 4 + wid;
    if (n >= NN) return;
    float si = s2I[n], sjn = s2J[n];
    int c = lane < CLS ? lane : 0;
    float p = __expf(lrelu(si + sjn));
    float asum = p;
    float acc = __half2float(fea2h[(size_t)n * CLS + c]) * p;
    int beg = row_off[n], end = row_off[n + 1];
    int e = beg;
    for (; e + 8 <= end; e += 8) {
        int s0 = csr[e + 0], s1 = csr[e + 1], s2 = csr[e + 2], s3 = csr[e + 3];
        int s4 = csr[e + 4], s5 = csr[e + 5], s6 = csr[e + 6], s7 = csr[e + 7];
        float a0 = s2J[s0], a1 = s2J[s1], a2 = s2J[s2], a3 = s2J[s3];
        float a4 = s2J[s4], a5 = s2J[s5], a6 = s2J[s6], a7 = s2J[s7];
        __half f0 = fea2h[(size_t)s0 * CLS + c];
        __half f1 = fea2h[(size_t)s1 * CLS + c];
        __half f2 = fea2h[(size_t)s2 * CLS + c];
        __half f3 = fea2h[(size_t)s3 * CLS + c];
        __half f4 = fea2h[(size_t)s4 * CLS + c];
        __half f5 = fea2h[(size_t)s5 * CLS + c];
        __half f6 = fea2h[(size_t)s6 * CLS + c];
        __half f7 = fea2h[(size_t)s7 * CLS + c];
        float p0 = __expf(lrelu(si + a0));
        float p1 = __expf(lrelu(si + a1));
        float p2 = __expf(lrelu(si + a2));
        float p3 = __expf(lrelu(si + a3));
        float p4 = __expf(lrelu(si + a4));
        float p5 = __expf(lrelu(si + a5));
        float p6 = __expf(lrelu(si + a6));
        float p7 = __expf(lrelu(si + a7));
        asum += ((p0 + p1) + (p2 + p3)) + ((p4 + p5) + (p6 + p7));
        acc += (__half2float(f0) * p0 + __half2float(f1) * p1
              + __half2float(f2) * p2 + __half2float(f3) * p3)
             + (__half2float(f4) * p4 + __half2float(f5) * p5
              + __half2float(f6) * p6 + __half2float(f7) * p7);
    }
    for (; e + 4 <= end; e += 4) {
        int s0 = csr[e], s1 = csr[e + 1], s2 = csr[e + 2], s3 = csr[e + 3];
        float p0 = __expf(lrelu(si + s2J[s0]));
        float p1 = __expf(lrelu(si + s2J[s1]));
        float p2 = __expf(lrelu(si + s2J[s2]));
        float p3 = __expf(lrelu(si + s2J[s3]));
        __half f0 = fea2h[(size_t)s0 * CLS + c];
        __half f1 = fea2h[(size_t)s1 * CLS + c];
        __half f2 = fea2h[(size_t)s2 * CLS + c];
        __half f3 = fea2h[(size_t)s3 * CLS + c];
        asum += (p0 + p1) + (p2 + p3);
        acc += __half2float(f0) * p0 + __half2float(f1) * p1
             + __half2float(f2) * p2 + __half2float(f3) * p3;
    }
    for (; e < end; ++e) {
        int s = csr[e];
        float pe = __expf(lrelu(si + s2J[s]));
        asum += pe;
        acc += __half2float(fea2h[(size_t)s * CLS + c]) * pe;
    }
    float row = acc / (asum + 1e-16f) + bias2[c];
    float v = (lane < CLS) ? row : -3.0e38f;
    float vm = v;
    #pragma unroll
    for (int off = 32; off; off >>= 1) vm = fmaxf(vm, __shfl_xor(vm, off));
    float ex = (lane < CLS) ? __expf(v - vm) : 0.f;
    float es = ex;
    #pragma unroll
    for (int off = 32; off; off >>= 1) es += __shfl_xor(es, off);
    if (lane < CLS) out[(size_t)n * CLS + lane] = ex / es;
}

extern "C" void kernel_launch(void* const* d_in, const int* in_sizes, int n_in,
                              void* d_out, int out_size, void* d_ws, size_t ws_size,
                              hipStream_t stream) {
    const float* x     = (const float*)d_in[0];
    const int*   ei    = (const int*)d_in[1];
    const float* w1    = (const float*)d_in[2];
    const float* b1    = (const float*)d_in[3];
    const float* att1  = (const float*)d_in[4];
    const float* bias1 = (const float*)d_in[5];
    const float* w2    = (const float*)d_in[6];
    const float* b2    = (const float*)d_in[7];
    const float* att2  = (const float*)d_in[8];
    const float* bias2 = (const float*)d_in[9];
    const int* src = ei;
    const int* dst = ei + NE;
    float* out = (float*)d_out;

    char* p = (char*)d_ws;
    auto alloc = [&](size_t bytes) {
        char* r = p;
        p += (bytes + 255) & ~(size_t)255;
        return r;
    };
    __half* fea1h = (__half*)alloc((size_t)NN * F1 * 2);
    __half* h1h   = (__half*)alloc((size_t)NN * F1 * 2);
    float* sI1    = (float*)alloc((size_t)NN * 4 * 4);
    float* sJ1    = (float*)alloc((size_t)NN * 4 * 4);
    __half* fea2h = (__half*)alloc((size_t)NN * CLS * 2);
    float* s2I    = (float*)alloc((size_t)NN * 4);
    float* s2J    = (float*)alloc((size_t)NN * 4);
    int*   deg    = (int*)alloc((size_t)NN * 4);
    int*   row_off= (int*)alloc((size_t)(NN + 1) * 4);
    int*   bsum   = (int*)alloc((size_t)NB * 4);
    int*   bpref  = (int*)alloc((size_t)NB * 4);
    int*   ord    = (int*)alloc((size_t)NE * 4);
    int*   csr    = (int*)alloc((size_t)NE * 4);
    float* ep1    = (float*)alloc((size_t)NE * 4 * 4);

    hipMemsetAsync(deg, 0, (size_t)NN * 4, stream);

    dim3 g1((NN + GBM - 1) / GBM, 4);
    gemm1_k<<<g1, 256, 0, stream>>>(x, w1, b1, att1, fea1h, sI1, sJ1);
    hist_k<<<(NE + 255) / 256, 256, 0, stream>>>(dst, deg, ord);
    scan1_k<<<NB, 1024, 0, stream>>>(deg, row_off, bsum);
    scan2_k<<<1, 64, 0, stream>>>(bsum, bpref);
    scan3_k<<<NB, 1024, 0, stream>>>(row_off, bpref);
    scatter_k<<<(NE + 255) / 256, 256, 0, stream>>>(src, dst, ord, row_off,
                                                    sI1, sJ1, csr, (float4*)ep1);
    agg1_k<<<(NN + 3) / 4, 256, 0, stream>>>(fea1h, sI1, sJ1, ep1, row_off, csr, bias1, h1h);
    gemm2_k<<<(NN + G2M - 1) / G2M, 256, 0, stream>>>(h1h, w2, b2, att2, fea2h, s2I, s2J);
    agg2_k<<<(NN + 3) / 4, 256, 0, stream>>>(fea2h, s2I, s2J, row_off, csr, bias2, out);
}

// Round 14
// 217.420 us; speedup vs baseline: 1.1918x; 1.0314x over previous
//
#include <hip/hip_runtime.h>
#include <hip/hip_fp16.h>

#define NN 50000
#define NE 800000
#define INFEAT 128
#define F1 256
#define HID 64
#define CLS 40
#define NEGS 0.2f
#define NB 49    // ceil(NN+1 / 1024)
#define GBM 128
#define GB1 1564 // 391 row-blocks * 4 heads
#define HB  1563 // ceil(NE / 512) hist blocks

__device__ __forceinline__ float lrelu(float x) { return x > 0.0f ? x : NEGS * x; }

struct alignas(8) H4 { __half2 a, b; };
struct alignas(16) H8 { __half2 a, b, c, d; };

typedef __attribute__((ext_vector_type(8))) _Float16 f16x8;
typedef __attribute__((ext_vector_type(4))) float f32x4;

// ---------------- fused GEMM1 (MFMA fp16) + edge histogram ----------------
__global__ __launch_bounds__(256) void gemm1_hist_k(const float* __restrict__ A,
                                                    const float* __restrict__ W,
                                                    const float* __restrict__ b,
                                                    const float* __restrict__ att1,
                                                    __half* __restrict__ feah,
                                                    float* __restrict__ sI,
                                                    float* __restrict__ sJ,
                                                    const int* __restrict__ dst,
                                                    int* __restrict__ deg,
                                                    int* __restrict__ ord) {
    __shared__ __align__(16) _Float16 As[128][40];
    __shared__ __align__(16) _Float16 Ws[64][40];
    int bx = blockIdx.x;
    int tid = threadIdx.x;
    if (bx >= GB1) {
        // -------- histogram path --------
        int base = (bx - GB1) * 512;
        int e0 = base + tid, e1 = base + 256 + tid;
        if (e0 < NE) ord[e0] = atomicAdd(&deg[dst[e0]], 1);
        if (e1 < NE) ord[e1] = atomicAdd(&deg[dst[e1]], 1);
        return;
    }
    // -------- gemm1 path --------
    int wid = tid >> 6, lane = tid & 63;
    int row0 = (bx >> 2) * GBM;
    int head = bx & 3;
    int colB = head * 64;
    int lr = lane & 15;
    int lg = lane >> 4;

    f32x4 acc[2][4];
    #pragma unroll
    for (int rt = 0; rt < 2; ++rt)
        #pragma unroll
        for (int ct = 0; ct < 4; ++ct) acc[rt][ct] = (f32x4){0.f, 0.f, 0.f, 0.f};

    int wcol = tid & 63;
    int wkg  = tid >> 6;

    for (int k0 = 0; k0 < INFEAT; k0 += 32) {
        #pragma unroll
        for (int i = 0; i < 4; ++i) {
            int q = tid + 256 * i;
            int r = q >> 3;
            int c4 = (q & 7) * 4;
            int grow = row0 + r;
            float4 v = make_float4(0.f, 0.f, 0.f, 0.f);
            if (grow < NN) v = *(const float4*)&A[(size_t)grow * INFEAT + k0 + c4];
            As[r][c4 + 0] = (_Float16)v.x; As[r][c4 + 1] = (_Float16)v.y;
            As[r][c4 + 2] = (_Float16)v.z; As[r][c4 + 3] = (_Float16)v.w;
        }
        {
            f16x8 wv;
            #pragma unroll
            for (int j = 0; j < 8; ++j)
                wv[j] = (_Float16)W[(size_t)(k0 + wkg * 8 + j) * F1 + colB + wcol];
            *(f16x8*)&Ws[wcol][wkg * 8] = wv;
        }
        __syncthreads();
        f16x8 afrag[2], bfrag[4];
        #pragma unroll
        for (int rt = 0; rt < 2; ++rt)
            afrag[rt] = *(const f16x8*)&As[wid * 32 + rt * 16 + lr][lg * 8];
        #pragma unroll
        for (int ct = 0; ct < 4; ++ct)
            bfrag[ct] = *(const f16x8*)&Ws[ct * 16 + lr][lg * 8];
        #pragma unroll
        for (int rt = 0; rt < 2; ++rt)
            #pragma unroll
            for (int ct = 0; ct < 4; ++ct)
                acc[rt][ct] = __builtin_amdgcn_mfma_f32_16x16x32_f16(
                    afrag[rt], bfrag[ct], acc[rt][ct], 0, 0, 0);
        __syncthreads();
    }
    float aIv[4], aJv[4], bv[4];
    #pragma unroll
    for (int ct = 0; ct < 4; ++ct) {
        int cin = ct * 16 + lr;
        aIv[ct] = att1[head * 2 * HID + cin];
        aJv[ct] = att1[head * 2 * HID + HID + cin];
        bv[ct]  = b[colB + cin];
    }
    #pragma unroll
    for (int rt = 0; rt < 2; ++rt) {
        #pragma unroll
        for (int i = 0; i < 4; ++i) {
            int grow = row0 + wid * 32 + rt * 16 + lg * 4 + i;
            float o[4];
            float sIp = 0.f, sJp = 0.f;
            #pragma unroll
            for (int ct = 0; ct < 4; ++ct) {
                o[ct] = acc[rt][ct][i] + bv[ct];
                sIp += o[ct] * aIv[ct];
                sJp += o[ct] * aJv[ct];
            }
            #pragma unroll
            for (int off = 1; off < 16; off <<= 1) {
                sIp += __shfl_xor(sIp, off);
                sJp += __shfl_xor(sJp, off);
            }
            if (grow < NN) {
                #pragma unroll
                for (int ct = 0; ct < 4; ++ct)
                    feah[(size_t)grow * F1 + colB + ct * 16 + lr] = __float2half(o[ct]);
                if (lr == 0) {
                    sI[grow * 4 + head] = sIp;
                    sJ[grow * 4 + head] = sJp;
                }
            }
        }
    }
}

// ---------------- scan1: per-block exclusive scan (also writes gid==NN) ----------------
__global__ __launch_bounds__(1024) void scan1_k(const int* __restrict__ deg,
                                                int* __restrict__ row_off,
                                                int* __restrict__ bsum) {
    __shared__ int tmp[1024];
    int tid = threadIdx.x;
    int gid = blockIdx.x * 1024 + tid;
    int v = (gid < NN) ? deg[gid] : 0;
    tmp[tid] = v;
    __syncthreads();
    #pragma unroll
    for (int off = 1; off < 1024; off <<= 1) {
        int t = (tid >= off) ? tmp[tid - off] : 0;
        __syncthreads();
        tmp[tid] += t;
        __syncthreads();
    }
    if (gid <= NN) row_off[gid] = tmp[tid] - v;   // block-local exclusive
    if (tid == 1023) bsum[blockIdx.x] = tmp[1023];
}

__global__ void scan2_k(const int* __restrict__ bsum, int* __restrict__ bpref) {
    int tid = threadIdx.x;
    int orig = (tid < NB) ? bsum[tid] : 0;
    int v = orig;
    #pragma unroll
    for (int off = 1; off < 64; off <<= 1) {
        int t = __shfl_up(v, off);
        if (tid >= off) v += t;
    }
    if (tid < NB) bpref[tid] = v - orig;   // exclusive block prefix
}

// ---------------- scatter: atomic-free, 2 edges/thread, fused ep1 ----------------
#define SC_T (NE / 2)
__global__ void scatter_k(const int* __restrict__ src, const int* __restrict__ dst,
                          const int* __restrict__ ord, const int* __restrict__ row_off,
                          const int* __restrict__ bpref,
                          const float* __restrict__ sI, const float* __restrict__ sJ,
                          int* __restrict__ csr, float4* __restrict__ ep4) {
    int t = blockIdx.x * blockDim.x + threadIdx.x;
    if (t >= SC_T) return;
    int e0 = t, e1 = t + SC_T;
    int s0 = src[e0], s1 = src[e1];
    int d0 = dst[e0], d1 = dst[e1];
    int p0 = row_off[d0] + bpref[d0 >> 10] + ord[e0];
    int p1 = row_off[d1] + bpref[d1 >> 10] + ord[e1];
    float4 si0 = *(const float4*)&sI[d0 * 4];
    float4 si1 = *(const float4*)&sI[d1 * 4];
    float4 sj0 = *(const float4*)&sJ[s0 * 4];
    float4 sj1 = *(const float4*)&sJ[s1 * 4];
    float4 r0, r1;
    r0.x = __expf(lrelu(si0.x + sj0.x)); r0.y = __expf(lrelu(si0.y + sj0.y));
    r0.z = __expf(lrelu(si0.z + sj0.z)); r0.w = __expf(lrelu(si0.w + sj0.w));
    r1.x = __expf(lrelu(si1.x + sj1.x)); r1.y = __expf(lrelu(si1.y + sj1.y));
    r1.z = __expf(lrelu(si1.z + sj1.z)); r1.w = __expf(lrelu(si1.w + sj1.w));
    csr[p0] = s0; csr[p1] = s1;
    ep4[p0] = r0; ep4[p1] = r1;
}

// ---------------- layer-1 aggregation: fp16 gathers, fp16 h1 output ----------------
__global__ __launch_bounds__(256, 6) void agg1_k(const __half* __restrict__ feah,
                                                 const float* __restrict__ sI,
                                                 const float* __restrict__ sJ,
                                                 const float* __restrict__ epf,
                                                 const int* __restrict__ row_off,
                                                 const int* __restrict__ bpref,
                                                 const int* __restrict__ csr,
                                                 const float* __restrict__ bias,
                                                 __half* __restrict__ out) {
    int wid = threadIdx.x >> 6, lane = threadIdx.x & 63;
    int n = blockIdx.x * 4 + wid;
    if (n >= NN) return;
    int h = lane >> 4;
    int c = lane * 4;
    float p = __expf(lrelu(sI[n * 4 + h] + sJ[n * 4 + h]));
    float asum = p;
    H4 vs = *(const H4*)&feah[(size_t)n * F1 + c];
    float2 sx = __half22float2(vs.a), sy = __half22float2(vs.b);
    float4 acc = make_float4(sx.x * p, sx.y * p, sy.x * p, sy.y * p);
    int beg = row_off[n] + bpref[n >> 10];
    int end = row_off[n + 1] + bpref[(n + 1) >> 10];
    int e = beg;
    for (; e + 8 <= end; e += 8) {
        int s0 = csr[e + 0], s1 = csr[e + 1], s2 = csr[e + 2], s3 = csr[e + 3];
        int s4 = csr[e + 4], s5 = csr[e + 5], s6 = csr[e + 6], s7 = csr[e + 7];
        float p0 = epf[(e + 0) * 4 + h], p1 = epf[(e + 1) * 4 + h];
        float p2 = epf[(e + 2) * 4 + h], p3 = epf[(e + 3) * 4 + h];
        float p4 = epf[(e + 4) * 4 + h], p5 = epf[(e + 5) * 4 + h];
        float p6 = epf[(e + 6) * 4 + h], p7 = epf[(e + 7) * 4 + h];
        H4 v0 = *(const H4*)&feah[(size_t)s0 * F1 + c];
        H4 v1 = *(const H4*)&feah[(size_t)s1 * F1 + c];
        H4 v2 = *(const H4*)&feah[(size_t)s2 * F1 + c];
        H4 v3 = *(const H4*)&feah[(size_t)s3 * F1 + c];
        H4 v4 = *(const H4*)&feah[(size_t)s4 * F1 + c];
        H4 v5 = *(const H4*)&feah[(size_t)s5 * F1 + c];
        H4 v6 = *(const H4*)&feah[(size_t)s6 * F1 + c];
        H4 v7 = *(const H4*)&feah[(size_t)s7 * F1 + c];
        asum += ((p0 + p1) + (p2 + p3)) + ((p4 + p5) + (p6 + p7));
        float2 x0 = __half22float2(v0.a), y0 = __half22float2(v0.b);
        float2 x1 = __half22float2(v1.a), y1 = __half22float2(v1.b);
        float2 x2 = __half22float2(v2.a), y2 = __half22float2(v2.b);
        float2 x3 = __half22float2(v3.a), y3 = __half22float2(v3.b);
        float2 x4 = __half22float2(v4.a), y4 = __half22float2(v4.b);
        float2 x5 = __half22float2(v5.a), y5 = __half22float2(v5.b);
        float2 x6 = __half22float2(v6.a), y6 = __half22float2(v6.b);
        float2 x7 = __half22float2(v7.a), y7 = __half22float2(v7.b);
        acc.x += (x0.x * p0 + x1.x * p1 + x2.x * p2 + x3.x * p3)
               + (x4.x * p4 + x5.x * p5 + x6.x * p6 + x7.x * p7);
        acc.y += (x0.y * p0 + x1.y * p1 + x2.y * p2 + x3.y * p3)
               + (x4.y * p4 + x5.y * p5 + x6.y * p6 + x7.y * p7);
        acc.z += (y0.x * p0 + y1.x * p1 + y2.x * p2 + y3.x * p3)
               + (y4.x * p4 + y5.x * p5 + y6.x * p6 + y7.x * p7);
        acc.w += (y0.y * p0 + y1.y * p1 + y2.y * p2 + y3.y * p3)
               + (y4.y * p4 + y5.y * p5 + y6.y * p6 + y7.y * p7);
    }
    for (; e + 4 <= end; e += 4) {
        int s0 = csr[e], s1 = csr[e + 1], s2 = csr[e + 2], s3 = csr[e + 3];
        float p0 = epf[(e + 0) * 4 + h], p1 = epf[(e + 1) * 4 + h];
        float p2 = epf[(e + 2) * 4 + h], p3 = epf[(e + 3) * 4 + h];
        H4 v0 = *(const H4*)&feah[(size_t)s0 * F1 + c];
        H4 v1 = *(const H4*)&feah[(size_t)s1 * F1 + c];
        H4 v2 = *(const H4*)&feah[(size_t)s2 * F1 + c];
        H4 v3 = *(const H4*)&feah[(size_t)s3 * F1 + c];
        asum += (p0 + p1) + (p2 + p3);
        float2 x0 = __half22float2(v0.a), y0 = __half22float2(v0.b);
        float2 x1 = __half22float2(v1.a), y1 = __half22float2(v1.b);
        float2 x2 = __half22float2(v2.a), y2 = __half22float2(v2.b);
        float2 x3 = __half22float2(v3.a), y3 = __half22float2(v3.b);
        acc.x += x0.x * p0 + x1.x * p1 + x2.x * p2 + x3.x * p3;
        acc.y += x0.y * p0 + x1.y * p1 + x2.y * p2 + x3.y * p3;
        acc.z += y0.x * p0 + y1.x * p1 + y2.x * p2 + y3.x * p3;
        acc.w += y0.y * p0 + y1.y * p1 + y2.y * p2 + y3.y * p3;
    }
    for (; e < end; ++e) {
        int s = csr[e];
        float pe = epf[e * 4 + h];
        asum += pe;
        H4 v = *(const H4*)&feah[(size_t)s * F1 + c];
        float2 x = __half22float2(v.a), y = __half22float2(v.b);
        acc.x += x.x * pe; acc.y += x.y * pe;
        acc.z += y.x * pe; acc.w += y.y * pe;
    }
    float inv = 1.0f / (asum + 1e-16f);
    float4 bv = *(const float4*)&bias[c];
    H4 o4;
    o4.a = __floats2half2_rn(fmaxf(acc.x * inv + bv.x, 0.f),
                             fmaxf(acc.y * inv + bv.y, 0.f));
    o4.b = __floats2half2_rn(fmaxf(acc.z * inv + bv.z, 0.f),
                             fmaxf(acc.w * inv + bv.w, 0.f));
    *(H4*)&out[(size_t)n * F1 + c] = o4;
}

// ---------------- GEMM2 via MFMA fp16 ----------------
#define G2M 128
__global__ __launch_bounds__(256) void gemm2_k(const __half* __restrict__ h1h,
                                               const float* __restrict__ W2,
                                               const float* __restrict__ b2,
                                               const float* __restrict__ att2,
                                               __half* __restrict__ fea2h,
                                               float* __restrict__ s2I,
                                               float* __restrict__ s2J) {
    __shared__ __align__(16) _Float16 Ws2[48][264];
    __shared__ __align__(16) _Float16 As2[128][40];
    int tid = threadIdx.x;
    int wid = tid >> 6, lane = tid & 63;
    int lr = lane & 15, lg = lane >> 4;
    int row0 = blockIdx.x * G2M;
    for (int q = tid; q < 48 * 32; q += 256) {
        int col = q >> 5;
        int kg  = q & 31;
        f16x8 wv;
        #pragma unroll
        for (int j = 0; j < 8; ++j) {
            int k = kg * 8 + j;
            wv[j] = (col < CLS) ? (_Float16)W2[(size_t)k * CLS + col] : (_Float16)0.f;
        }
        *(f16x8*)&Ws2[col][kg * 8] = wv;
    }
    f32x4 acc[2][3];
    #pragma unroll
    for (int rt = 0; rt < 2; ++rt)
        #pragma unroll
        for (int ct = 0; ct < 3; ++ct) acc[rt][ct] = (f32x4){0.f, 0.f, 0.f, 0.f};

    for (int k0 = 0; k0 < F1; k0 += 32) {
        #pragma unroll
        for (int i = 0; i < 2; ++i) {
            int q = tid + 256 * i;
            int r = q >> 2;
            int c8 = (q & 3) * 8;
            int grow = row0 + r;
            f16x8 v;
            if (grow < NN) v = *(const f16x8*)&h1h[(size_t)grow * F1 + k0 + c8];
            else {
                #pragma unroll
                for (int j = 0; j < 8; ++j) v[j] = (_Float16)0.f;
            }
            *(f16x8*)&As2[r][c8] = v;
        }
        __syncthreads();
        f16x8 af[2], bf[3];
        #pragma unroll
        for (int rt = 0; rt < 2; ++rt)
            af[rt] = *(const f16x8*)&As2[wid * 32 + rt * 16 + lr][lg * 8];
        #pragma unroll
        for (int ct = 0; ct < 3; ++ct)
            bf[ct] = *(const f16x8*)&Ws2[ct * 16 + lr][k0 + lg * 8];
        #pragma unroll
        for (int rt = 0; rt < 2; ++rt)
            #pragma unroll
            for (int ct = 0; ct < 3; ++ct)
                acc[rt][ct] = __builtin_amdgcn_mfma_f32_16x16x32_f16(
                    af[rt], bf[ct], acc[rt][ct], 0, 0, 0);
        __syncthreads();
    }
    float bcol[3], aIc[3], aJc[3];
    bool valid[3];
    #pragma unroll
    for (int ct = 0; ct < 3; ++ct) {
        int col = ct * 16 + lr;
        valid[ct] = col < CLS;
        int cc = valid[ct] ? col : 0;
        bcol[ct] = b2[cc];
        aIc[ct] = valid[ct] ? att2[cc] : 0.f;
        aJc[ct] = valid[ct] ? att2[CLS + cc] : 0.f;
    }
    #pragma unroll
    for (int rt = 0; rt < 2; ++rt) {
        #pragma unroll
        for (int i = 0; i < 4; ++i) {
            int grow = row0 + wid * 32 + rt * 16 + lg * 4 + i;
            float o[3];
            float sIp = 0.f, sJp = 0.f;
            #pragma unroll
            for (int ct = 0; ct < 3; ++ct) {
                o[ct] = acc[rt][ct][i] + bcol[ct];
                sIp += o[ct] * aIc[ct];
                sJp += o[ct] * aJc[ct];
            }
            #pragma unroll
            for (int off = 1; off < 16; off <<= 1) {
                sIp += __shfl_xor(sIp, off);
                sJp += __shfl_xor(sJp, off);
            }
            if (grow < NN) {
                #pragma unroll
                for (int ct = 0; ct < 3; ++ct)
                    if (valid[ct])
                        fea2h[(size_t)grow * CLS + ct * 16 + lr] = __float2half(o[ct]);
                if (lr == 0) {
                    s2I[grow] = sIp;
                    s2J[grow] = sJp;
                }
            }
        }
    }
}

// ---------------- layer-2 aggregation + bias + row softmax ----------------
__global__ __launch_bounds__(256) void agg2_k(const __half* __restrict__ fea2h,
                                              const float* __restrict__ s2I,
                                              const float* __restrict__ s2J,
                                              const int* __restrict__ row_off,
                                              const int* __restrict__ bpref,
                                              const int* __restrict__ csr,
                                              const float* __restrict__ bias2,
                                              float* __restrict__ out) {
    int wid = threadIdx.x >> 6, lane = threadIdx.x & 63;
    int n = blockIdx.x * 4 + wid;
    if (n >= NN) return;
    float si = s2I[n], sjn = s2J[n];
    int c = lane < CLS ? lane : 0;
    float p = __expf(lrelu(si + sjn));
    float asum = p;
    float acc = __half2float(fea2h[(size_t)n * CLS + c]) * p;
    int beg = row_off[n] + bpref[n >> 10];
    int end = row_off[n + 1] + bpref[(n + 1) >> 10];
    int e = beg;
    for (; e + 8 <= end; e += 8) {
        int s0 = csr[e + 0], s1 = csr[e + 1], s2 = csr[e + 2], s3 = csr[e + 3];
        int s4 = csr[e + 4], s5 = csr[e + 5], s6 = csr[e + 6], s7 = csr[e + 7];
        float a0 = s2J[s0], a1 = s2J[s1], a2 = s2J[s2], a3 = s2J[s3];
        float a4 = s2J[s4], a5 = s2J[s5], a6 = s2J[s6], a7 = s2J[s7];
        __half f0 = fea2h[(size_t)s0 * CLS + c];
        __half f1 = fea2h[(size_t)s1 * CLS + c];
        __half f2 = fea2h[(size_t)s2 * CLS + c];
        __half f3 = fea2h[(size_t)s3 * CLS + c];
        __half f4 = fea2h[(size_t)s4 * CLS + c];
        __half f5 = fea2h[(size_t)s5 * CLS + c];
        __half f6 = fea2h[(size_t)s6 * CLS + c];
        __half f7 = fea2h[(size_t)s7 * CLS + c];
        float p0 = __expf(lrelu(si + a0));
        float p1 = __expf(lrelu(si + a1));
        float p2 = __expf(lrelu(si + a2));
        float p3 = __expf(lrelu(si + a3));
        float p4 = __expf(lrelu(si + a4));
        float p5 = __expf(lrelu(si + a5));
        float p6 = __expf(lrelu(si + a6));
        float p7 = __expf(lrelu(si + a7));
        asum += ((p0 + p1) + (p2 + p3)) + ((p4 + p5) + (p6 + p7));
        acc += (__half2float(f0) * p0 + __half2float(f1) * p1
              + __half2float(f2) * p2 + __half2float(f3) * p3)
             + (__half2float(f4) * p4 + __half2float(f5) * p5
              + __half2float(f6) * p6 + __half2float(f7) * p7);
    }
    for (; e + 4 <= end; e += 4) {
        int s0 = csr[e], s1 = csr[e + 1], s2 = csr[e + 2], s3 = csr[e + 3];
        float p0 = __expf(lrelu(si + s2J[s0]));
        float p1 = __expf(lrelu(si + s2J[s1]));
        float p2 = __expf(lrelu(si + s2J[s2]));
        float p3 = __expf(lrelu(si + s2J[s3]));
        __half f0 = fea2h[(size_t)s0 * CLS + c];
        __half f1 = fea2h[(size_t)s1 * CLS + c];
        __half f2 = fea2h[(size_t)s2 * CLS + c];
        __half f3 = fea2h[(size_t)s3 * CLS + c];
        asum += (p0 + p1) + (p2 + p3);
        acc += __half2float(f0) * p0 + __half2float(f1) * p1
             + __half2float(f2) * p2 + __half2float(f3) * p3;
    }
    for (; e < end; ++e) {
        int s = csr[e];
        float pe = __expf(lrelu(si + s2J[s]));
        asum += pe;
        acc += __half2float(fea2h[(size_t)s * CLS + c]) * pe;
    }
    float row = acc / (asum + 1e-16f) + bias2[c];
    float v = (lane < CLS) ? row : -3.0e38f;
    float vm = v;
    #pragma unroll
    for (int off = 32; off; off >>= 1) vm = fmaxf(vm, __shfl_xor(vm, off));
    float ex = (lane < CLS) ? __expf(v - vm) : 0.f;
    float es = ex;
    #pragma unroll
    for (int off = 32; off; off >>= 1) es += __shfl_xor(es, off);
    if (lane < CLS) out[(size_t)n * CLS + lane] = ex / es;
}

extern "C" void kernel_launch(void* const* d_in, const int* in_sizes, int n_in,
                              void* d_out, int out_size, void* d_ws, size_t ws_size,
                              hipStream_t stream) {
    const float* x     = (const float*)d_in[0];
    const int*   ei    = (const int*)d_in[1];
    const float* w1    = (const float*)d_in[2];
    const float* b1    = (const float*)d_in[3];
    const float* att1  = (const float*)d_in[4];
    const float* bias1 = (const float*)d_in[5];
    const float* w2    = (const float*)d_in[6];
    const float* b2    = (const float*)d_in[7];
    const float* att2  = (const float*)d_in[8];
    const float* bias2 = (const float*)d_in[9];
    const int* src = ei;
    const int* dst = ei + NE;
    float* out = (float*)d_out;

    char* p = (char*)d_ws;
    auto alloc = [&](size_t bytes) {
        char* r = p;
        p += (bytes + 255) & ~(size_t)255;
        return r;
    };
    __half* fea1h = (__half*)alloc((size_t)NN * F1 * 2);
    __half* h1h   = (__half*)alloc((size_t)NN * F1 * 2);
    float* sI1    = (float*)alloc((size_t)NN * 4 * 4);
    float* sJ1    = (float*)alloc((size_t)NN * 4 * 4);
    __half* fea2h = (__half*)alloc((size_t)NN * CLS * 2);
    float* s2I    = (float*)alloc((size_t)NN * 4);
    float* s2J    = (float*)alloc((size_t)NN * 4);
    int*   deg    = (int*)alloc((size_t)NN * 4);
    int*   row_off= (int*)alloc((size_t)(NN + 1) * 4);
    int*   bsum   = (int*)alloc((size_t)NB * 4);
    int*   bpref  = (int*)alloc((size_t)NB * 4);
    int*   ord    = (int*)alloc((size_t)NE * 4);
    int*   csr    = (int*)alloc((size_t)NE * 4);
    float* ep1    = (float*)alloc((size_t)NE * 4 * 4);

    hipMemsetAsync(deg, 0, (size_t)NN * 4, stream);

    gemm1_hist_k<<<GB1 + HB, 256, 0, stream>>>(x, w1, b1, att1, fea1h, sI1, sJ1,
                                               dst, deg, ord);
    scan1_k<<<NB, 1024, 0, stream>>>(deg, row_off, bsum);
    scan2_k<<<1, 64, 0, stream>>>(bsum, bpref);
    scatter_k<<<(SC_T + 255) / 256, 256, 0, stream>>>(src, dst, ord, row_off, bpref,
                                                      sI1, sJ1, csr, (float4*)ep1);
    agg1_k<<<(NN + 3) / 4, 256, 0, stream>>>(fea1h, sI1, sJ1, ep1, row_off, bpref,
                                             csr, bias1, h1h);
    gemm2_k<<<(NN + G2M - 1) / G2M, 256, 0, stream>>>(h1h, w2, b2, att2, fea2h, s2I, s2J);
    agg2_k<<<(NN + 3) / 4, 256, 0, stream>>>(fea2h, s2I, s2J, row_off, bpref,
                                             csr, bias2, out);
}